// Round 1
// baseline (1311.029 us; speedup 1.0000x reference)
//
#include <hip/hip_runtime.h>

typedef unsigned short u16;
typedef unsigned int u32;
typedef __bf16 bf16x8_t __attribute__((ext_vector_type(8)));
typedef float f32x4_t __attribute__((ext_vector_type(4)));

// ---- constants (problem shape) ----
// B=2, L=2048, D_MODEL=1024, D_INNER=2048, D_STATE=16, D_CONV=4
// ROWS = B*L = 4096; proj width padded 2080 -> 2176 (17*128)

__device__ __forceinline__ u16 f2bf(float f) {
  u32 u = __float_as_uint(f);
  return (u16)((u + 0x7fffu + ((u >> 16) & 1u)) >> 16);  // RNE
}
__device__ __forceinline__ float bf2f(u16 h) { return __uint_as_float(((u32)h) << 16); }

__device__ __forceinline__ void async_ld16(const u16* g, u16* l) {
  __builtin_amdgcn_global_load_lds((const __attribute__((address_space(1))) void*)g,
                                   (__attribute__((address_space(3))) void*)l, 16, 0, 0);
}

// ---------------- converters ----------------
__global__ void k_cvt(const float* __restrict__ in, u16* __restrict__ out, int n4) {
  int g = blockIdx.x * 256 + threadIdx.x;
  if (g >= n4) return;
  float4 v = reinterpret_cast<const float4*>(in)[g];
  u32 lo = (u32)f2bf(v.x) | ((u32)f2bf(v.y) << 16);
  u32 hi = (u32)f2bf(v.z) | ((u32)f2bf(v.w) << 16);
  reinterpret_cast<uint2*>(out)[g] = make_uint2(lo, hi);
}

// W_x (2080 x 2048) -> bf16 padded to 2176 rows (trailing rows zero)
__global__ void k_cvt_pad(const float* __restrict__ in, u16* __restrict__ out,
                          int n4_valid, int n4_total) {
  int g = blockIdx.x * 256 + threadIdx.x;
  if (g >= n4_total) return;
  u32 lo = 0, hi = 0;
  if (g < n4_valid) {
    float4 v = reinterpret_cast<const float4*>(in)[g];
    lo = (u32)f2bf(v.x) | ((u32)f2bf(v.y) << 16);
    hi = (u32)f2bf(v.z) | ((u32)f2bf(v.w) << 16);
  }
  reinterpret_cast<uint2*>(out)[g] = make_uint2(lo, hi);
}

// ---------------- bf16 MFMA GEMM: C[M,N] = A[M,K] * B[N,K]^T ----------------
// m97 structure: 128x128 tile, BK=64, 4 waves (2x2), 4x4 16x16x32 frags,
// global_load_lds width=16 staging, single-buffer LDS.
template <bool WB, bool WF>
__global__ __launch_bounds__(256, 2) void k_gemm_bt(
    const u16* __restrict__ A, int lda, const u16* __restrict__ B, int ldb,
    float* __restrict__ Cf, u16* __restrict__ Cb, int ldc, int K) {
  __shared__ __align__(16) u16 sA[128 * 64];
  __shared__ __align__(16) u16 sB[128 * 64];
  const int tid = threadIdx.x;
  const int lane = tid & 63;
  const int wave = tid >> 6;
  const size_t tm = (size_t)blockIdx.y * 128;
  const size_t tn = (size_t)blockIdx.x * 128;
  const int wm = (wave & 1) * 64;
  const int wn = (wave >> 1) * 64;
  const int mrow = lane & 15;
  const int quad = lane >> 4;

  f32x4_t acc[4][4];
#pragma unroll
  for (int i = 0; i < 4; ++i)
#pragma unroll
    for (int j = 0; j < 4; ++j) {
      acc[i][j][0] = 0.f; acc[i][j][1] = 0.f; acc[i][j][2] = 0.f; acc[i][j][3] = 0.f;
    }

  for (int k0 = 0; k0 < K; k0 += 64) {
#pragma unroll
    for (int j = 0; j < 4; ++j) {
      int idx = j * 256 + tid;          // 16B chunk index; LDS dst = base + lane*16 (wave-uniform)
      int row = idx >> 3;
      int col = (idx & 7) << 3;
      async_ld16(A + (tm + row) * (size_t)lda + (k0 + col), sA + (size_t)idx * 8);
      async_ld16(B + (tn + row) * (size_t)ldb + (k0 + col), sB + (size_t)idx * 8);
    }
    __syncthreads();  // compiler emits s_waitcnt vmcnt(0) before barrier
#pragma unroll
    for (int kk = 0; kk < 64; kk += 32) {
      bf16x8_t af[4], bfr[4];
#pragma unroll
      for (int i = 0; i < 4; ++i)
        af[i] = *reinterpret_cast<const bf16x8_t*>(sA + (wm + i * 16 + mrow) * 64 + kk + quad * 8);
#pragma unroll
      for (int i = 0; i < 4; ++i)
        bfr[i] = *reinterpret_cast<const bf16x8_t*>(sB + (wn + i * 16 + mrow) * 64 + kk + quad * 8);
#pragma unroll
      for (int i = 0; i < 4; ++i)
#pragma unroll
        for (int j = 0; j < 4; ++j)
          acc[i][j] = __builtin_amdgcn_mfma_f32_16x16x32_bf16(af[i], bfr[j], acc[i][j], 0, 0, 0);
    }
    __syncthreads();
  }

  // C/D layout: col = lane&15, row = quad*4 + reg  [measured m89/m91]
#pragma unroll
  for (int i = 0; i < 4; ++i)
#pragma unroll
    for (int j = 0; j < 4; ++j) {
      size_t r0 = tm + wm + i * 16 + quad * 4;
      size_t c = tn + wn + j * 16 + mrow;
#pragma unroll
      for (int r = 0; r < 4; ++r) {
        float v = acc[i][j][r];
        if (WF) Cf[(r0 + r) * (size_t)ldc + c] = v;
        if (WB) Cb[(r0 + r) * (size_t)ldc + c] = f2bf(v);
      }
    }
}

// ---------------- depthwise causal conv(4) + silu ----------------
// u[b,l,d] = silu(conv_b[d] + sum_k xs[b, l-3+k, d] * conv_w[d,k]); xs = xz[:, :, 0:2048]
__global__ void k_conv_silu(const u16* __restrict__ xz, const float* __restrict__ cw,
                            const float* __restrict__ cb, u16* __restrict__ u) {
  int g = blockIdx.x * 256 + threadIdx.x;  // 2*2048*2048
  int d = g & 2047;
  int l = (g >> 11) & 2047;
  int b = g >> 22;
  float acc = cb[d];
#pragma unroll
  for (int k = 0; k < 4; ++k) {
    int lp = l + k - 3;
    if (lp >= 0) acc += bf2f(xz[((size_t)(b * 2048 + lp) << 12) + d]) * cw[d * 4 + k];
  }
  float s = acc / (1.f + __expf(-acc));
  u[g] = f2bf(s);
}

// ---------------- chunked selective scan ----------------
// thread map (passes 1/3): block = 256 thr = 16 d x 16 n; wave holds 4 d (quad) x 16 n
// grid = (D/16=128, NC=16, B=2); chunk length 128
__device__ __forceinline__ float softplus_f(float x) {
  return x > 20.f ? x : log1pf(__expf(x));
}

__global__ void k_scan1(const float* __restrict__ dpre, const float* __restrict__ bdt,
                        const u16* __restrict__ u, const float* __restrict__ proj,
                        const float* __restrict__ A_log, float* __restrict__ sF,
                        float* __restrict__ aF) {
  int lane = threadIdx.x & 63, wave = threadIdx.x >> 6;
  int n = lane & 15, dq = lane >> 4;
  int d = blockIdx.x * 16 + wave * 4 + dq;
  int c = blockIdx.y, b = blockIdx.z;
  float A = -expf(A_log[d * 16 + n]);
  float bd = bdt[d];
  float s = 0.f, ap = 1.f;
  int t0 = c * 128;
  for (int t = t0; t < t0 + 128; ++t) {
    size_t rb = (size_t)(b * 2048 + t);
    float delta = softplus_f(dpre[rb * 2048 + d] + bd);
    float uv = bf2f(u[rb * 2048 + d]);
    float Bv = proj[rb * 2176 + 2048 + n];
    float dA = __expf(delta * A);
    s = s * dA + delta * Bv * uv;
    ap *= dA;
  }
  size_t o = ((size_t)((b * 16 + c) * 2048 + d) << 4) + n;
  sF[o] = s;
  aF[o] = ap;
}

__global__ void k_scan_carry(const float* __restrict__ sF, const float* __restrict__ aF,
                             float* __restrict__ carry) {
  int g = blockIdx.x * 256 + threadIdx.x;  // 2*2048*16 = 65536
  int b = g >> 15;
  int dn = g & 32767;
  float S = 0.f;
#pragma unroll
  for (int c = 0; c < 16; ++c) {
    size_t idx = ((size_t)(b * 16 + c) << 15) + dn;
    carry[idx] = S;
    S = S * aF[idx] + sF[idx];
  }
}

__global__ void k_scan3(const float* __restrict__ dpre, const float* __restrict__ bdt,
                        const u16* __restrict__ u, const float* __restrict__ proj,
                        const float* __restrict__ A_log, const float* __restrict__ carry,
                        float* __restrict__ y) {
  int lane = threadIdx.x & 63, wave = threadIdx.x >> 6;
  int n = lane & 15, dq = lane >> 4;
  int d = blockIdx.x * 16 + wave * 4 + dq;
  int c = blockIdx.y, b = blockIdx.z;
  float A = -expf(A_log[d * 16 + n]);
  float bd = bdt[d];
  float s = carry[((size_t)((b * 16 + c) * 2048 + d) << 4) + n];
  int t0 = c * 128;
  for (int t = t0; t < t0 + 128; ++t) {
    size_t rb = (size_t)(b * 2048 + t);
    float delta = softplus_f(dpre[rb * 2048 + d] + bd);
    float uv = bf2f(u[rb * 2048 + d]);
    float Bv = proj[rb * 2176 + 2048 + n];
    float Cv = proj[rb * 2176 + 2064 + n];
    float dA = __expf(delta * A);
    s = s * dA + delta * Bv * uv;
    float p = s * Cv;
    p += __shfl_xor(p, 1);
    p += __shfl_xor(p, 2);
    p += __shfl_xor(p, 4);
    p += __shfl_xor(p, 8);
    if (n == 0) y[rb * 2048 + d] = p;  // lanes 0,16,32,48 -> 4 consecutive d
  }
}

// ---------------- gate: ybf = (y + u*D) * silu(z) ----------------
__global__ void k_gate(const float* __restrict__ y, const u16* __restrict__ u,
                       const float* __restrict__ Dv, const u16* __restrict__ xz,
                       u16* __restrict__ ybf) {
  int g = blockIdx.x * 256 + threadIdx.x;  // 8.4M
  int d = g & 2047;
  size_t row = (size_t)g >> 11;  // b*2048 + l
  float yy = y[g] + bf2f(u[g]) * Dv[d];
  float z = bf2f(xz[(row << 12) + 2048 + d]);
  yy *= z / (1.f + __expf(-z));
  ybf[g] = f2bf(yy);
}

// ---------------- residual + layernorm ----------------
__global__ void k_ln(const float* __restrict__ pre, const float* __restrict__ x,
                     const float* __restrict__ gam, const float* __restrict__ bet,
                     float* __restrict__ out) {
  int row = blockIdx.x, tid = threadIdx.x;
  size_t base = (size_t)row * 1024 + tid * 4;
  float4 v = *reinterpret_cast<const float4*>(pre + base);
  float4 r = *reinterpret_cast<const float4*>(x + base);
  v.x += r.x; v.y += r.y; v.z += r.z; v.w += r.w;
  float s = v.x + v.y + v.z + v.w;
  float s2 = v.x * v.x + v.y * v.y + v.z * v.z + v.w * v.w;
#pragma unroll
  for (int o = 32; o >= 1; o >>= 1) {
    s += __shfl_xor(s, o);
    s2 += __shfl_xor(s2, o);
  }
  __shared__ float red[8];
  int lane = tid & 63, wv = tid >> 6;
  if (lane == 0) { red[wv] = s; red[4 + wv] = s2; }
  __syncthreads();
  s = red[0] + red[1] + red[2] + red[3];
  s2 = red[4] + red[5] + red[6] + red[7];
  float mu = s * (1.f / 1024.f);
  float var = s2 * (1.f / 1024.f) - mu * mu;
  float rstd = rsqrtf(var + 1e-5f);
  float4 gg = *reinterpret_cast<const float4*>(gam + tid * 4);
  float4 bb = *reinterpret_cast<const float4*>(bet + tid * 4);
  float4 o;
  o.x = (v.x - mu) * rstd * gg.x + bb.x;
  o.y = (v.y - mu) * rstd * gg.y + bb.y;
  o.z = (v.z - mu) * rstd * gg.z + bb.z;
  o.w = (v.w - mu) * rstd * gg.w + bb.w;
  *reinterpret_cast<float4*>(out + base) = o;
}

extern "C" void kernel_launch(void* const* d_in, const int* in_sizes, int n_in,
                              void* d_out, int out_size, void* d_ws, size_t ws_size,
                              hipStream_t stream) {
  (void)in_sizes; (void)n_in; (void)out_size; (void)ws_size;
  const float* x = (const float*)d_in[0];
  const float* W_in = (const float*)d_in[1];
  const float* conv_w = (const float*)d_in[2];
  const float* conv_b = (const float*)d_in[3];
  const float* W_x = (const float*)d_in[4];
  const float* W_dt = (const float*)d_in[5];
  const float* b_dt = (const float*)d_in[6];
  const float* A_log = (const float*)d_in[7];
  const float* Dv = (const float*)d_in[8];
  const float* W_out = (const float*)d_in[9];
  const float* ln_g = (const float*)d_in[10];
  const float* ln_b = (const float*)d_in[11];
  float* out = (float*)d_out;

  // ---- workspace layout (~209 MB, lifetime-aliased) ----
  char* p = (char*)d_ws;
  u16* xz_bf = (u16*)p;      p += (size_t)4096 * 4096 * 2;  // live: gemm1 .. gate
  u16* u_bf = (u16*)p;       p += (size_t)4096 * 2048 * 2;  // conv .. gate
  float* proj = (float*)p;   p += (size_t)4096 * 2176 * 4;  // gemm2 .. scan3 (then outpre)
  u16* projbf = (u16*)p;     p += (size_t)4096 * 2176 * 2;  // gemm2 .. gemm3
  float* dpre = (float*)p;   p += (size_t)4096 * 2048 * 4;  // gemm3 .. scan3 (then ybf)
  float* yscan = (float*)p;  p += (size_t)4096 * 2048 * 4;  // scan3 .. gate
  u16* Wx_bf = (u16*)p;      p += (size_t)2176 * 2048 * 2;
  u16* Wdt_bf = (u16*)p;     p += (size_t)2048 * 2048 * 2;
  u16* Wout_bf = (u16*)p;    p += (size_t)1024 * 2048 * 2;
  u16* x_bf = (u16*)p;       p += (size_t)4096 * 1024 * 2;  // dead after gemm1 -> scan scratch
  u16* Win_bf = (u16*)p;     p += (size_t)4096 * 1024 * 2;  // dead after gemm1 -> scan scratch
  float* sF = (float*)x_bf;                     // 4 MB each (2*16*2048*16 fp32)
  float* aF = sF + (size_t)2 * 16 * 2048 * 16;
  float* carry = aF + (size_t)2 * 16 * 2048 * 16;  // extends into Win_bf region (dead)
  float* outpre = proj;        // alias: proj dead after scan3
  u16* ybf = (u16*)dpre;       // alias: dpre dead after scan3

  // 1) weight/activation bf16 conversion
  k_cvt<<<4096, 256, 0, stream>>>(x, x_bf, 1048576);
  k_cvt<<<4096, 256, 0, stream>>>(W_in, Win_bf, 1048576);
  k_cvt_pad<<<4352, 256, 0, stream>>>(W_x, Wx_bf, 1064960, 1114112);
  k_cvt<<<4096, 256, 0, stream>>>(W_dt, Wdt_bf, 1048576);
  k_cvt<<<2048, 256, 0, stream>>>(W_out, Wout_bf, 524288);

  // 2) xz = x @ W_in^T   (4096 x 4096, K=1024) -> bf16
  k_gemm_bt<true, false><<<dim3(32, 32), 256, 0, stream>>>(x_bf, 1024, Win_bf, 1024,
                                                           nullptr, xz_bf, 4096, 1024);
  // 3) depthwise conv + silu -> u (bf16)
  k_conv_silu<<<32768, 256, 0, stream>>>(xz_bf, conv_w, conv_b, u_bf);
  // 4) proj = u @ W_x^T  (4096 x 2176pad, K=2048) -> fp32 (B,C for scan) + bf16 (d_in)
  k_gemm_bt<true, true><<<dim3(17, 32), 256, 0, stream>>>(u_bf, 2048, Wx_bf, 2048,
                                                          proj, projbf, 2176, 2048);
  // 5) dpre = d_in @ W_dt^T (4096 x 2048, K=2048) -> fp32
  k_gemm_bt<false, true><<<dim3(16, 32), 256, 0, stream>>>(projbf, 2176, Wdt_bf, 2048,
                                                           dpre, nullptr, 2048, 2048);
  // 6) chunked selective scan (16 chunks x 128 steps)
  k_scan1<<<dim3(128, 16, 2), 256, 0, stream>>>(dpre, b_dt, u_bf, proj, A_log, sF, aF);
  k_scan_carry<<<256, 256, 0, stream>>>(sF, aF, carry);
  k_scan3<<<dim3(128, 16, 2), 256, 0, stream>>>(dpre, b_dt, u_bf, proj, A_log, carry, yscan);
  // 7) gate: ybf = (y + u*D) * silu(z)
  k_gate<<<32768, 256, 0, stream>>>(yscan, u_bf, Dv, xz_bf, ybf);
  // 8) outpre = ybf @ W_out^T (4096 x 1024, K=2048)
  k_gemm_bt<false, true><<<dim3(8, 32), 256, 0, stream>>>(ybf, 2048, Wout_bf, 2048,
                                                          outpre, nullptr, 1024, 2048);
  // 9) residual + layernorm -> d_out
  k_ln<<<4096, 256, 0, stream>>>(outpre, x, ln_g, ln_b, out);
}

// Round 2
// 484.088 us; speedup vs baseline: 2.7082x; 2.7082x over previous
//
#include <hip/hip_runtime.h>

typedef unsigned short u16;
typedef unsigned int u32;
typedef __bf16 bf16x8_t __attribute__((ext_vector_type(8)));
typedef float f32x4_t __attribute__((ext_vector_type(4)));

// ---- constants (problem shape) ----
// B=2, L=2048, D_MODEL=1024, D_INNER=2048, D_STATE=16, D_CONV=4
// ROWS = B*L = 4096; proj width padded 2080 -> 2176 (17*128)
// scan: NC=64 chunks x CL=32 steps

#define NCH 64
#define CLEN 32

__device__ __forceinline__ u16 f2bf(float f) {
  u32 u = __float_as_uint(f);
  return (u16)((u + 0x7fffu + ((u >> 16) & 1u)) >> 16);  // RNE
}
__device__ __forceinline__ float bf2f(u16 h) { return __uint_as_float(((u32)h) << 16); }

__device__ __forceinline__ void async_ld16(const u16* g, u16* l) {
  __builtin_amdgcn_global_load_lds((const __attribute__((address_space(1))) void*)g,
                                   (__attribute__((address_space(3))) void*)l, 16, 0, 0);
}

// ---------------- converters ----------------
__global__ void k_cvt(const float* __restrict__ in, u16* __restrict__ out, int n4) {
  int g = blockIdx.x * 256 + threadIdx.x;
  if (g >= n4) return;
  float4 v = reinterpret_cast<const float4*>(in)[g];
  u32 lo = (u32)f2bf(v.x) | ((u32)f2bf(v.y) << 16);
  u32 hi = (u32)f2bf(v.z) | ((u32)f2bf(v.w) << 16);
  reinterpret_cast<uint2*>(out)[g] = make_uint2(lo, hi);
}

// W_x (2080 x 2048) -> bf16 padded to 2176 rows (trailing rows zero)
__global__ void k_cvt_pad(const float* __restrict__ in, u16* __restrict__ out,
                          int n4_valid, int n4_total) {
  int g = blockIdx.x * 256 + threadIdx.x;
  if (g >= n4_total) return;
  u32 lo = 0, hi = 0;
  if (g < n4_valid) {
    float4 v = reinterpret_cast<const float4*>(in)[g];
    lo = (u32)f2bf(v.x) | ((u32)f2bf(v.y) << 16);
    hi = (u32)f2bf(v.z) | ((u32)f2bf(v.w) << 16);
  }
  reinterpret_cast<uint2*>(out)[g] = make_uint2(lo, hi);
}

// ---------------- bf16 MFMA GEMM: C[M,N] = A[M,K] * B[N,K]^T ----------------
// m97 structure: 128x128 tile, BK=64, 4 waves (2x2), 4x4 16x16x32 frags.
// fp32 output restricted to columns >= fcol0 (written at ldcf with col-fcol0).
template <bool WB, bool WF>
__global__ __launch_bounds__(256, 2) void k_gemm_bt(
    const u16* __restrict__ A, int lda, const u16* __restrict__ B, int ldb,
    float* __restrict__ Cf, int fcol0, int ldcf,
    u16* __restrict__ Cb, int ldc, int K) {
  __shared__ __align__(16) u16 sA[128 * 64];
  __shared__ __align__(16) u16 sB[128 * 64];
  const int tid = threadIdx.x;
  const int lane = tid & 63;
  const int wave = tid >> 6;
  const size_t tm = (size_t)blockIdx.y * 128;
  const size_t tn = (size_t)blockIdx.x * 128;
  const int wm = (wave & 1) * 64;
  const int wn = (wave >> 1) * 64;
  const int mrow = lane & 15;
  const int quad = lane >> 4;

  f32x4_t acc[4][4];
#pragma unroll
  for (int i = 0; i < 4; ++i)
#pragma unroll
    for (int j = 0; j < 4; ++j) {
      acc[i][j][0] = 0.f; acc[i][j][1] = 0.f; acc[i][j][2] = 0.f; acc[i][j][3] = 0.f;
    }

  for (int k0 = 0; k0 < K; k0 += 64) {
#pragma unroll
    for (int j = 0; j < 4; ++j) {
      int idx = j * 256 + tid;
      int row = idx >> 3;
      int col = (idx & 7) << 3;
      async_ld16(A + (tm + row) * (size_t)lda + (k0 + col), sA + (size_t)idx * 8);
      async_ld16(B + (tn + row) * (size_t)ldb + (k0 + col), sB + (size_t)idx * 8);
    }
    __syncthreads();
#pragma unroll
    for (int kk = 0; kk < 64; kk += 32) {
      bf16x8_t af[4], bfr[4];
#pragma unroll
      for (int i = 0; i < 4; ++i)
        af[i] = *reinterpret_cast<const bf16x8_t*>(sA + (wm + i * 16 + mrow) * 64 + kk + quad * 8);
#pragma unroll
      for (int i = 0; i < 4; ++i)
        bfr[i] = *reinterpret_cast<const bf16x8_t*>(sB + (wn + i * 16 + mrow) * 64 + kk + quad * 8);
#pragma unroll
      for (int i = 0; i < 4; ++i)
#pragma unroll
        for (int j = 0; j < 4; ++j)
          acc[i][j] = __builtin_amdgcn_mfma_f32_16x16x32_bf16(af[i], bfr[j], acc[i][j], 0, 0, 0);
    }
    __syncthreads();
  }

  // C/D layout: col = lane&15, row = quad*4 + reg  [measured m89/m91]
#pragma unroll
  for (int i = 0; i < 4; ++i)
#pragma unroll
    for (int j = 0; j < 4; ++j) {
      size_t r0 = tm + wm + i * 16 + quad * 4;
      size_t c = tn + wn + j * 16 + mrow;
#pragma unroll
      for (int r = 0; r < 4; ++r) {
        float v = acc[i][j][r];
        if (WF && (int)c >= fcol0) Cf[(r0 + r) * (size_t)ldcf + (c - fcol0)] = v;
        if (WB) Cb[(r0 + r) * (size_t)ldc + c] = f2bf(v);
      }
    }
}

// ---------------- depthwise causal conv(4) + silu ----------------
__global__ void k_conv_silu(const u16* __restrict__ xz, const float* __restrict__ cw,
                            const float* __restrict__ cb, u16* __restrict__ u) {
  int g = blockIdx.x * 256 + threadIdx.x;  // 2*2048*2048
  int d = g & 2047;
  int l = (g >> 11) & 2047;
  int b = g >> 22;
  float acc = cb[d];
#pragma unroll
  for (int k = 0; k < 4; ++k) {
    int lp = l + k - 3;
    if (lp >= 0) acc += bf2f(xz[((size_t)(b * 2048 + lp) << 12) + d]) * cw[d * 4 + k];
  }
  float s = acc / (1.f + __expf(-acc));
  u[g] = f2bf(s);
}

// ---------------- chunked selective scan ----------------
// one thread per d-channel, all 16 n-states in registers.
// grid = (D/256=8, NC, B), block 256. chunk length CLEN.
__device__ __forceinline__ float softplus_fast(float x) {
  return __logf(1.f + __expf(x));
}

__global__ void k_scan1(const u16* __restrict__ dpre, const float* __restrict__ bdt,
                        const u16* __restrict__ u, const float* __restrict__ projBC,
                        const float* __restrict__ A_log, float* __restrict__ sF,
                        float* __restrict__ aF) {
  int d = blockIdx.x * 256 + threadIdx.x;
  int c = blockIdx.y, b = blockIdx.z;
  float A[16], s[16], ap[16];
#pragma unroll
  for (int q = 0; q < 4; ++q) {
    float4 al = reinterpret_cast<const float4*>(A_log + d * 16)[q];
    A[q * 4 + 0] = -__expf(al.x); A[q * 4 + 1] = -__expf(al.y);
    A[q * 4 + 2] = -__expf(al.z); A[q * 4 + 3] = -__expf(al.w);
  }
#pragma unroll
  for (int n = 0; n < 16; ++n) { s[n] = 0.f; ap[n] = 1.f; }
  float bd = bdt[d];
  int t0 = c * CLEN;
  for (int t = t0; t < t0 + CLEN; ++t) {
    size_t rb = (size_t)(b * 2048 + t);
    float delta = softplus_fast(bf2f(dpre[rb * 2048 + d]) + bd);
    float du = delta * bf2f(u[rb * 2048 + d]);
    // B row: wave-uniform address -> scalar loads
    const float4* Bp = reinterpret_cast<const float4*>(projBC + rb * 128);
    float4 B0 = Bp[0], B1 = Bp[1], B2 = Bp[2], B3 = Bp[3];
    float Bv[16] = {B0.x, B0.y, B0.z, B0.w, B1.x, B1.y, B1.z, B1.w,
                    B2.x, B2.y, B2.z, B2.w, B3.x, B3.y, B3.z, B3.w};
#pragma unroll
    for (int n = 0; n < 16; ++n) {
      float dA = __expf(delta * A[n]);
      s[n] = fmaf(s[n], dA, du * Bv[n]);
      ap[n] *= dA;
    }
  }
  size_t o = ((size_t)((b * NCH + c) * 2048 + d)) << 4;
#pragma unroll
  for (int q = 0; q < 4; ++q) {
    reinterpret_cast<float4*>(sF + o)[q] = make_float4(s[q * 4], s[q * 4 + 1], s[q * 4 + 2], s[q * 4 + 3]);
    reinterpret_cast<float4*>(aF + o)[q] = make_float4(ap[q * 4], ap[q * 4 + 1], ap[q * 4 + 2], ap[q * 4 + 3]);
  }
}

__global__ void k_scan_carry(const float* __restrict__ sF, const float* __restrict__ aF,
                             float* __restrict__ carry) {
  int g = blockIdx.x * 256 + threadIdx.x;  // 2 * 2048*16 = 65536
  int b = g >> 15;
  int dn = g & 32767;
  float S = 0.f;
#pragma unroll 4
  for (int c = 0; c < NCH; ++c) {
    size_t idx = ((size_t)(b * NCH + c) << 15) + dn;
    carry[idx] = S;
    S = S * aF[idx] + sF[idx];
  }
}

// scan3: recompute with carry-in, fuse  y = (scan + u*D) * silu(z)  -> bf16 (gemm4 input)
__global__ void k_scan3(const u16* __restrict__ dpre, const float* __restrict__ bdt,
                        const u16* __restrict__ u, const float* __restrict__ projBC,
                        const float* __restrict__ A_log, const float* __restrict__ carry,
                        const float* __restrict__ Dvec, const u16* __restrict__ xz,
                        u16* __restrict__ ybf) {
  int d = blockIdx.x * 256 + threadIdx.x;
  int c = blockIdx.y, b = blockIdx.z;
  float A[16], s[16];
#pragma unroll
  for (int q = 0; q < 4; ++q) {
    float4 al = reinterpret_cast<const float4*>(A_log + d * 16)[q];
    A[q * 4 + 0] = -__expf(al.x); A[q * 4 + 1] = -__expf(al.y);
    A[q * 4 + 2] = -__expf(al.z); A[q * 4 + 3] = -__expf(al.w);
  }
  size_t o = ((size_t)((b * NCH + c) * 2048 + d)) << 4;
#pragma unroll
  for (int q = 0; q < 4; ++q) {
    float4 cv = reinterpret_cast<const float4*>(carry + o)[q];
    s[q * 4] = cv.x; s[q * 4 + 1] = cv.y; s[q * 4 + 2] = cv.z; s[q * 4 + 3] = cv.w;
  }
  float bd = bdt[d];
  float Dd = Dvec[d];
  int t0 = c * CLEN;
  for (int t = t0; t < t0 + CLEN; ++t) {
    size_t rb = (size_t)(b * 2048 + t);
    float delta = softplus_fast(bf2f(dpre[rb * 2048 + d]) + bd);
    float uv = bf2f(u[rb * 2048 + d]);
    float du = delta * uv;
    const float4* Bp = reinterpret_cast<const float4*>(projBC + rb * 128);
    float4 B0 = Bp[0], B1 = Bp[1], B2 = Bp[2], B3 = Bp[3];
    float4 C0 = Bp[4], C1 = Bp[5], C2 = Bp[6], C3 = Bp[7];
    float Bv[16] = {B0.x, B0.y, B0.z, B0.w, B1.x, B1.y, B1.z, B1.w,
                    B2.x, B2.y, B2.z, B2.w, B3.x, B3.y, B3.z, B3.w};
    float Cv[16] = {C0.x, C0.y, C0.z, C0.w, C1.x, C1.y, C1.z, C1.w,
                    C2.x, C2.y, C2.z, C2.w, C3.x, C3.y, C3.z, C3.w};
    float yv = 0.f;
#pragma unroll
    for (int n = 0; n < 16; ++n) {
      float dA = __expf(delta * A[n]);
      s[n] = fmaf(s[n], dA, du * Bv[n]);
      yv = fmaf(s[n], Cv[n], yv);
    }
    yv += uv * Dd;
    float z = bf2f(xz[(rb << 12) + 2048 + d]);
    yv *= z / (1.f + __expf(-z));
    ybf[rb * 2048 + d] = f2bf(yv);
  }
}

// ---------------- residual + layernorm ----------------
__global__ void k_ln(const float* __restrict__ pre, const float* __restrict__ x,
                     const float* __restrict__ gam, const float* __restrict__ bet,
                     float* __restrict__ out) {
  int row = blockIdx.x, tid = threadIdx.x;
  size_t base = (size_t)row * 1024 + tid * 4;
  float4 v = *reinterpret_cast<const float4*>(pre + base);
  float4 r = *reinterpret_cast<const float4*>(x + base);
  v.x += r.x; v.y += r.y; v.z += r.z; v.w += r.w;
  float s = v.x + v.y + v.z + v.w;
  float s2 = v.x * v.x + v.y * v.y + v.z * v.z + v.w * v.w;
#pragma unroll
  for (int o = 32; o >= 1; o >>= 1) {
    s += __shfl_xor(s, o);
    s2 += __shfl_xor(s2, o);
  }
  __shared__ float red[8];
  int lane = tid & 63, wv = tid >> 6;
  if (lane == 0) { red[wv] = s; red[4 + wv] = s2; }
  __syncthreads();
  s = red[0] + red[1] + red[2] + red[3];
  s2 = red[4] + red[5] + red[6] + red[7];
  float mu = s * (1.f / 1024.f);
  float var = s2 * (1.f / 1024.f) - mu * mu;
  float rstd = rsqrtf(var + 1e-5f);
  float4 gg = *reinterpret_cast<const float4*>(gam + tid * 4);
  float4 bb = *reinterpret_cast<const float4*>(bet + tid * 4);
  float4 o;
  o.x = (v.x - mu) * rstd * gg.x + bb.x;
  o.y = (v.y - mu) * rstd * gg.y + bb.y;
  o.z = (v.z - mu) * rstd * gg.z + bb.z;
  o.w = (v.w - mu) * rstd * gg.w + bb.w;
  *reinterpret_cast<float4*>(out + base) = o;
}

extern "C" void kernel_launch(void* const* d_in, const int* in_sizes, int n_in,
                              void* d_out, int out_size, void* d_ws, size_t ws_size,
                              hipStream_t stream) {
  (void)in_sizes; (void)n_in; (void)out_size; (void)ws_size;
  const float* x = (const float*)d_in[0];
  const float* W_in = (const float*)d_in[1];
  const float* conv_w = (const float*)d_in[2];
  const float* conv_b = (const float*)d_in[3];
  const float* W_x = (const float*)d_in[4];
  const float* W_dt = (const float*)d_in[5];
  const float* b_dt = (const float*)d_in[6];
  const float* A_log = (const float*)d_in[7];
  const float* Dv = (const float*)d_in[8];
  const float* W_out = (const float*)d_in[9];
  const float* ln_g = (const float*)d_in[10];
  const float* ln_b = (const float*)d_in[11];
  float* out = (float*)d_out;

  // ---- workspace layout (~192 MB, lifetime-aliased; old 209 MB layout passed) ----
  char* p = (char*)d_ws;
  u16* xz_bf = (u16*)p;      p += (size_t)4096 * 4096 * 2;   // gemm1 .. scan3 (z)
  u16* u_bf = (u16*)p;       p += (size_t)4096 * 2048 * 2;   // conv .. scan3
  float* projBC = (float*)p; p += (size_t)4096 * 128 * 4;    // gemm2 (B,C cols only) .. scan3
  u16* projbf = (u16*)p;     p += (size_t)4096 * 2176 * 2;   // gemm2 .. gemm3
  u16* dpre_bf = (u16*)p;    p += (size_t)4096 * 2048 * 2;   // gemm3 .. scan3
  u16* ybf = (u16*)p;        p += (size_t)4096 * 2048 * 2;   // scan3 .. gemm4
  float* sF = (float*)p;     p += (size_t)2 * NCH * 2048 * 16 * 4;  // scan1 .. carry
  float* aF = (float*)p;     p += (size_t)2 * NCH * 2048 * 16 * 4;  // scan1 .. carry
  float* carry = (float*)p;  p += (size_t)2 * NCH * 2048 * 16 * 4;  // carry .. scan3
  u16* Wx_bf = (u16*)p;      p += (size_t)2176 * 2048 * 2;
  u16* Wdt_bf = (u16*)p;     p += (size_t)2048 * 2048 * 2;
  u16* Wout_bf = (u16*)p;    p += (size_t)1024 * 2048 * 2;
  u16* x_bf = (u16*)p;       p += (size_t)4096 * 1024 * 2;   // cvt .. gemm1, then outpre
  u16* Win_bf = (u16*)p;     p += (size_t)4096 * 1024 * 2;   // cvt .. gemm1
  float* outpre = (float*)x_bf;  // alias: x_bf/Win_bf dead after gemm1 (16.8 MB)

  // 1) bf16 conversions
  k_cvt<<<4096, 256, 0, stream>>>(x, x_bf, 1048576);
  k_cvt<<<4096, 256, 0, stream>>>(W_in, Win_bf, 1048576);
  k_cvt_pad<<<4352, 256, 0, stream>>>(W_x, Wx_bf, 1064960, 1114112);
  k_cvt<<<4096, 256, 0, stream>>>(W_dt, Wdt_bf, 1048576);
  k_cvt<<<2048, 256, 0, stream>>>(W_out, Wout_bf, 524288);

  // 2) xz = x @ W_in^T   (4096 x 4096, K=1024) -> bf16
  k_gemm_bt<true, false><<<dim3(32, 32), 256, 0, stream>>>(
      x_bf, 1024, Win_bf, 1024, nullptr, 0, 0, xz_bf, 4096, 1024);
  // 3) depthwise conv + silu -> u (bf16)
  k_conv_silu<<<32768, 256, 0, stream>>>(xz_bf, conv_w, conv_b, u_bf);
  // 4) proj = u @ W_x^T  (4096 x 2176pad, K=2048): bf16 full (d_in) + fp32 cols 2048.. (B,C)
  k_gemm_bt<true, true><<<dim3(17, 32), 256, 0, stream>>>(
      u_bf, 2048, Wx_bf, 2048, projBC, 2048, 128, projbf, 2176, 2048);
  // 5) dpre = d_in @ W_dt^T (4096 x 2048, K=2048) -> bf16
  k_gemm_bt<true, false><<<dim3(16, 32), 256, 0, stream>>>(
      projbf, 2176, Wdt_bf, 2048, nullptr, 0, 0, dpre_bf, 2048, 2048);
  // 6) chunked selective scan (64 chunks x 32 steps), gate fused into pass 3
  k_scan1<<<dim3(8, NCH, 2), 256, 0, stream>>>(dpre_bf, b_dt, u_bf, projBC, A_log, sF, aF);
  k_scan_carry<<<256, 256, 0, stream>>>(sF, aF, carry);
  k_scan3<<<dim3(8, NCH, 2), 256, 0, stream>>>(dpre_bf, b_dt, u_bf, projBC, A_log, carry,
                                               Dv, xz_bf, ybf);
  // 7) outpre = ybf @ W_out^T (4096 x 1024, K=2048)
  k_gemm_bt<false, true><<<dim3(8, 32), 256, 0, stream>>>(
      ybf, 2048, Wout_bf, 2048, outpre, 0, 1024, nullptr, 0, 2048);
  // 8) residual + layernorm -> d_out
  k_ln<<<4096, 256, 0, stream>>>(outpre, x, ln_g, ln_b, out);
}

// Round 3
// 483.224 us; speedup vs baseline: 2.7131x; 1.0018x over previous
//
#include <hip/hip_runtime.h>

typedef unsigned short u16;
typedef unsigned int u32;
typedef __bf16 bf16x8_t __attribute__((ext_vector_type(8)));
typedef float f32x4_t __attribute__((ext_vector_type(4)));

// ---- constants (problem shape) ----
// B=2, L=2048, D_MODEL=1024, D_INNER=2048, D_STATE=16, D_CONV=4
// ROWS = B*L = 4096; proj width padded 2080 -> 2176 (17*128)
// scan: NC=64 chunks x CL=32 steps

#define NCH 64
#define CLEN 32

__device__ __forceinline__ u16 f2bf(float f) {
  u32 u = __float_as_uint(f);
  return (u16)((u + 0x7fffu + ((u >> 16) & 1u)) >> 16);  // RNE
}
__device__ __forceinline__ float bf2f(u16 h) { return __uint_as_float(((u32)h) << 16); }

__device__ __forceinline__ void async_ld16(const u16* g, u16* l) {
  __builtin_amdgcn_global_load_lds((const __attribute__((address_space(1))) void*)g,
                                   (__attribute__((address_space(3))) void*)l, 16, 0, 0);
}

// ---------------- fused converter: all 5 fp32->bf16 weight/act conversions ----------------
// ranges (in float4 units): x 0..1048576, W_in ..2097152, W_x(pad to 2176 rows) ..3211264,
// W_dt ..4259840, W_out ..4784128
__global__ void k_cvt_all(const float* __restrict__ x, u16* __restrict__ x_bf,
                          const float* __restrict__ W_in, u16* __restrict__ Win_bf,
                          const float* __restrict__ W_x, u16* __restrict__ Wx_bf,
                          const float* __restrict__ W_dt, u16* __restrict__ Wdt_bf,
                          const float* __restrict__ W_out, u16* __restrict__ Wout_bf) {
  int g = blockIdx.x * 256 + threadIdx.x;
  const float* src;
  u16* dst;
  int rel;
  bool valid = true;
  if (g < 1048576) { src = x; dst = x_bf; rel = g; }
  else if (g < 2097152) { src = W_in; dst = Win_bf; rel = g - 1048576; }
  else if (g < 3211264) { src = W_x; dst = Wx_bf; rel = g - 2097152; valid = rel < 1064960; }
  else if (g < 4259840) { src = W_dt; dst = Wdt_bf; rel = g - 3211264; }
  else if (g < 4784128) { src = W_out; dst = Wout_bf; rel = g - 4259840; }
  else return;
  u32 lo = 0, hi = 0;
  if (valid) {
    float4 v = reinterpret_cast<const float4*>(src)[rel];
    lo = (u32)f2bf(v.x) | ((u32)f2bf(v.y) << 16);
    hi = (u32)f2bf(v.z) | ((u32)f2bf(v.w) << 16);
  }
  reinterpret_cast<uint2*>(dst)[rel] = make_uint2(lo, hi);
}

// ---------------- bf16 MFMA GEMM: C[M,N] = A[M,K] * B[N,K]^T ----------------
// m97 structure: 128x128 tile, BK=64, 4 waves (2x2), 4x4 16x16x32 frags.
// DB=true: double-buffered LDS (64 KB) — prefetch tile k+1 during compute of k, so the
//   barrier's vmcnt(0) drain overlaps the 32-MFMA compute phase (for low-block-count grids).
// Split-K via gridDim.z: each z handles K columns starting at blockIdx.z*K; fp32 output
//   offset by blockIdx.z*fsplit.
template <bool WB, bool WF, bool DB>
__global__ __launch_bounds__(256, 2) void k_gemm_bt(
    const u16* __restrict__ A, int lda, const u16* __restrict__ B, int ldb,
    float* __restrict__ Cf, int fcol0, int ldcf, size_t fsplit,
    u16* __restrict__ Cb, int ldc, int K) {
  __shared__ __align__(16) u16 sA[(DB ? 2 : 1) * 128 * 64];
  __shared__ __align__(16) u16 sB[(DB ? 2 : 1) * 128 * 64];
  const int tid = threadIdx.x;
  const int lane = tid & 63;
  const int wave = tid >> 6;
  const size_t tm = (size_t)blockIdx.y * 128;
  const size_t tn = (size_t)blockIdx.x * 128;
  const int kbase = blockIdx.z * K;
  const int wm = (wave & 1) * 64;
  const int wn = (wave >> 1) * 64;
  const int mrow = lane & 15;
  const int quad = lane >> 4;

  f32x4_t acc[4][4];
#pragma unroll
  for (int i = 0; i < 4; ++i)
#pragma unroll
    for (int j = 0; j < 4; ++j) {
      acc[i][j][0] = 0.f; acc[i][j][1] = 0.f; acc[i][j][2] = 0.f; acc[i][j][3] = 0.f;
    }

  auto stage = [&](int k0, int buf) {
#pragma unroll
    for (int j = 0; j < 4; ++j) {
      int idx = j * 256 + tid;
      int row = idx >> 3;
      int col = (idx & 7) << 3;
      async_ld16(A + (tm + row) * (size_t)lda + (kbase + k0 + col), sA + buf * 8192 + (size_t)idx * 8);
      async_ld16(B + (tn + row) * (size_t)ldb + (kbase + k0 + col), sB + buf * 8192 + (size_t)idx * 8);
    }
  };
  auto compute = [&](int buf) {
    const u16* bA = sA + buf * 8192;
    const u16* bB = sB + buf * 8192;
#pragma unroll
    for (int kk = 0; kk < 64; kk += 32) {
      bf16x8_t af[4], bfr[4];
#pragma unroll
      for (int i = 0; i < 4; ++i)
        af[i] = *reinterpret_cast<const bf16x8_t*>(bA + (wm + i * 16 + mrow) * 64 + kk + quad * 8);
#pragma unroll
      for (int i = 0; i < 4; ++i)
        bfr[i] = *reinterpret_cast<const bf16x8_t*>(bB + (wn + i * 16 + mrow) * 64 + kk + quad * 8);
#pragma unroll
      for (int i = 0; i < 4; ++i)
#pragma unroll
        for (int j = 0; j < 4; ++j)
          acc[i][j] = __builtin_amdgcn_mfma_f32_16x16x32_bf16(af[i], bfr[j], acc[i][j], 0, 0, 0);
    }
  };

  if (DB) {
    const int nit = K >> 6;
    stage(0, 0);
    __syncthreads();  // drain prologue loads
    for (int it = 0; it < nit; ++it) {
      if (it + 1 < nit) stage((it + 1) << 6, (it + 1) & 1);  // async prefetch, in flight during MFMA
      compute(it & 1);
      __syncthreads();  // drains prefetch + ds_reads; guards buffer reuse
    }
  } else {
    for (int k0 = 0; k0 < K; k0 += 64) {
      stage(k0, 0);
      __syncthreads();
      compute(0);
      __syncthreads();
    }
  }

  // C/D layout: col = lane&15, row = quad*4 + reg  [measured m89/m91]
  if (WF) Cf += (size_t)blockIdx.z * fsplit;
#pragma unroll
  for (int i = 0; i < 4; ++i)
#pragma unroll
    for (int j = 0; j < 4; ++j) {
      size_t r0 = tm + wm + i * 16 + quad * 4;
      size_t c = tn + wn + j * 16 + mrow;
#pragma unroll
      for (int r = 0; r < 4; ++r) {
        float v = acc[i][j][r];
        if (WF && (int)c >= fcol0) Cf[(r0 + r) * (size_t)ldcf + (c - fcol0)] = v;
        if (WB) Cb[(r0 + r) * (size_t)ldc + c] = f2bf(v);
      }
    }
}

// ---------------- depthwise causal conv(4) + silu ----------------
__global__ void k_conv_silu(const u16* __restrict__ xz, const float* __restrict__ cw,
                            const float* __restrict__ cb, u16* __restrict__ u) {
  int g = blockIdx.x * 256 + threadIdx.x;  // 2*2048*2048
  int d = g & 2047;
  int l = (g >> 11) & 2047;
  int b = g >> 22;
  float acc = cb[d];
#pragma unroll
  for (int k = 0; k < 4; ++k) {
    int lp = l + k - 3;
    if (lp >= 0) acc += bf2f(xz[((size_t)(b * 2048 + lp) << 12) + d]) * cw[d * 4 + k];
  }
  float s = acc / (1.f + __expf(-acc));
  u[g] = f2bf(s);
}

// ---------------- chunked selective scan ----------------
// one thread per d-channel, all 16 n-states in registers.
// grid = (D/256=8, NC, B), block 256. chunk length CLEN.
__device__ __forceinline__ float softplus_fast(float x) {
  return __logf(1.f + __expf(x));
}

__global__ void k_scan1(const u16* __restrict__ dpre, const float* __restrict__ bdt,
                        const u16* __restrict__ u, const float* __restrict__ projBC,
                        const float* __restrict__ A_log, float* __restrict__ sF,
                        float* __restrict__ aF) {
  int d = blockIdx.x * 256 + threadIdx.x;
  int c = blockIdx.y, b = blockIdx.z;
  float A[16], s[16], ap[16];
#pragma unroll
  for (int q = 0; q < 4; ++q) {
    float4 al = reinterpret_cast<const float4*>(A_log + d * 16)[q];
    A[q * 4 + 0] = -__expf(al.x); A[q * 4 + 1] = -__expf(al.y);
    A[q * 4 + 2] = -__expf(al.z); A[q * 4 + 3] = -__expf(al.w);
  }
#pragma unroll
  for (int n = 0; n < 16; ++n) { s[n] = 0.f; ap[n] = 1.f; }
  float bd = bdt[d];
  int t0 = c * CLEN;
  for (int t = t0; t < t0 + CLEN; ++t) {
    size_t rb = (size_t)(b * 2048 + t);
    float delta = softplus_fast(bf2f(dpre[rb * 2048 + d]) + bd);
    float du = delta * bf2f(u[rb * 2048 + d]);
    const float4* Bp = reinterpret_cast<const float4*>(projBC + rb * 128);
    float4 B0 = Bp[0], B1 = Bp[1], B2 = Bp[2], B3 = Bp[3];
    float Bv[16] = {B0.x, B0.y, B0.z, B0.w, B1.x, B1.y, B1.z, B1.w,
                    B2.x, B2.y, B2.z, B2.w, B3.x, B3.y, B3.z, B3.w};
#pragma unroll
    for (int n = 0; n < 16; ++n) {
      float dA = __expf(delta * A[n]);
      s[n] = fmaf(s[n], dA, du * Bv[n]);
      ap[n] *= dA;
    }
  }
  size_t o = ((size_t)((b * NCH + c) * 2048 + d)) << 4;
#pragma unroll
  for (int q = 0; q < 4; ++q) {
    reinterpret_cast<float4*>(sF + o)[q] = make_float4(s[q * 4], s[q * 4 + 1], s[q * 4 + 2], s[q * 4 + 3]);
    reinterpret_cast<float4*>(aF + o)[q] = make_float4(ap[q * 4], ap[q * 4 + 1], ap[q * 4 + 2], ap[q * 4 + 3]);
  }
}

__global__ void k_scan_carry(const float* __restrict__ sF, const float* __restrict__ aF,
                             float* __restrict__ carry) {
  int g = blockIdx.x * 256 + threadIdx.x;  // 2 * 2048*16 = 65536
  int b = g >> 15;
  int dn = g & 32767;
  float S = 0.f;
#pragma unroll 4
  for (int c = 0; c < NCH; ++c) {
    size_t idx = ((size_t)(b * NCH + c) << 15) + dn;
    carry[idx] = S;
    S = S * aF[idx] + sF[idx];
  }
}

// scan3: recompute with carry-in, fuse  y = (scan + u*D) * silu(z)  -> bf16 (gemm4 input)
__global__ void k_scan3(const u16* __restrict__ dpre, const float* __restrict__ bdt,
                        const u16* __restrict__ u, const float* __restrict__ projBC,
                        const float* __restrict__ A_log, const float* __restrict__ carry,
                        const float* __restrict__ Dvec, const u16* __restrict__ xz,
                        u16* __restrict__ ybf) {
  int d = blockIdx.x * 256 + threadIdx.x;
  int c = blockIdx.y, b = blockIdx.z;
  float A[16], s[16];
#pragma unroll
  for (int q = 0; q < 4; ++q) {
    float4 al = reinterpret_cast<const float4*>(A_log + d * 16)[q];
    A[q * 4 + 0] = -__expf(al.x); A[q * 4 + 1] = -__expf(al.y);
    A[q * 4 + 2] = -__expf(al.z); A[q * 4 + 3] = -__expf(al.w);
  }
  size_t o = ((size_t)((b * NCH + c) * 2048 + d)) << 4;
#pragma unroll
  for (int q = 0; q < 4; ++q) {
    float4 cv = reinterpret_cast<const float4*>(carry + o)[q];
    s[q * 4] = cv.x; s[q * 4 + 1] = cv.y; s[q * 4 + 2] = cv.z; s[q * 4 + 3] = cv.w;
  }
  float bd = bdt[d];
  float Dd = Dvec[d];
  int t0 = c * CLEN;
  for (int t = t0; t < t0 + CLEN; ++t) {
    size_t rb = (size_t)(b * 2048 + t);
    float delta = softplus_fast(bf2f(dpre[rb * 2048 + d]) + bd);
    float uv = bf2f(u[rb * 2048 + d]);
    float du = delta * uv;
    const float4* Bp = reinterpret_cast<const float4*>(projBC + rb * 128);
    float4 B0 = Bp[0], B1 = Bp[1], B2 = Bp[2], B3 = Bp[3];
    float4 C0 = Bp[4], C1 = Bp[5], C2 = Bp[6], C3 = Bp[7];
    float Bv[16] = {B0.x, B0.y, B0.z, B0.w, B1.x, B1.y, B1.z, B1.w,
                    B2.x, B2.y, B2.z, B2.w, B3.x, B3.y, B3.z, B3.w};
    float Cv[16] = {C0.x, C0.y, C0.z, C0.w, C1.x, C1.y, C1.z, C1.w,
                    C2.x, C2.y, C2.z, C2.w, C3.x, C3.y, C3.z, C3.w};
    float yv = 0.f;
#pragma unroll
    for (int n = 0; n < 16; ++n) {
      float dA = __expf(delta * A[n]);
      s[n] = fmaf(s[n], dA, du * Bv[n]);
      yv = fmaf(s[n], Cv[n], yv);
    }
    yv += uv * Dd;
    float z = bf2f(xz[(rb << 12) + 2048 + d]);
    yv *= z / (1.f + __expf(-z));
    ybf[rb * 2048 + d] = f2bf(yv);
  }
}

// ---------------- residual + layernorm (sums 2 split-K partials) ----------------
__global__ void k_ln(const float* __restrict__ pre, const float* __restrict__ x,
                     const float* __restrict__ gam, const float* __restrict__ bet,
                     float* __restrict__ out) {
  int row = blockIdx.x, tid = threadIdx.x;
  size_t base = (size_t)row * 1024 + tid * 4;
  float4 v = *reinterpret_cast<const float4*>(pre + base);
  float4 p1 = *reinterpret_cast<const float4*>(pre + 4194304 + base);
  float4 r = *reinterpret_cast<const float4*>(x + base);
  v.x += p1.x + r.x; v.y += p1.y + r.y; v.z += p1.z + r.z; v.w += p1.w + r.w;
  float s = v.x + v.y + v.z + v.w;
  float s2 = v.x * v.x + v.y * v.y + v.z * v.z + v.w * v.w;
#pragma unroll
  for (int o = 32; o >= 1; o >>= 1) {
    s += __shfl_xor(s, o);
    s2 += __shfl_xor(s2, o);
  }
  __shared__ float red[8];
  int lane = tid & 63, wv = tid >> 6;
  if (lane == 0) { red[wv] = s; red[4 + wv] = s2; }
  __syncthreads();
  s = red[0] + red[1] + red[2] + red[3];
  s2 = red[4] + red[5] + red[6] + red[7];
  float mu = s * (1.f / 1024.f);
  float var = s2 * (1.f / 1024.f) - mu * mu;
  float rstd = rsqrtf(var + 1e-5f);
  float4 gg = *reinterpret_cast<const float4*>(gam + tid * 4);
  float4 bb = *reinterpret_cast<const float4*>(bet + tid * 4);
  float4 o;
  o.x = (v.x - mu) * rstd * gg.x + bb.x;
  o.y = (v.y - mu) * rstd * gg.y + bb.y;
  o.z = (v.z - mu) * rstd * gg.z + bb.z;
  o.w = (v.w - mu) * rstd * gg.w + bb.w;
  *reinterpret_cast<float4*>(out + base) = o;
}

extern "C" void kernel_launch(void* const* d_in, const int* in_sizes, int n_in,
                              void* d_out, int out_size, void* d_ws, size_t ws_size,
                              hipStream_t stream) {
  (void)in_sizes; (void)n_in; (void)out_size; (void)ws_size;
  const float* x = (const float*)d_in[0];
  const float* W_in = (const float*)d_in[1];
  const float* conv_w = (const float*)d_in[2];
  const float* conv_b = (const float*)d_in[3];
  const float* W_x = (const float*)d_in[4];
  const float* W_dt = (const float*)d_in[5];
  const float* b_dt = (const float*)d_in[6];
  const float* A_log = (const float*)d_in[7];
  const float* Dv = (const float*)d_in[8];
  const float* W_out = (const float*)d_in[9];
  const float* ln_g = (const float*)d_in[10];
  const float* ln_b = (const float*)d_in[11];
  float* out = (float*)d_out;

  // ---- workspace layout (~202 MB, lifetime-aliased) ----
  char* p = (char*)d_ws;
  u16* xz_bf = (u16*)p;      p += (size_t)4096 * 4096 * 2;   // gemm1 .. scan3 (z)
  u16* u_bf = (u16*)p;       p += (size_t)4096 * 2048 * 2;   // conv .. scan3
  float* projBC = (float*)p; p += (size_t)4096 * 128 * 4;    // gemm2 (B,C cols only) .. scan3
  u16* projbf = (u16*)p;     p += (size_t)4096 * 2176 * 2;   // gemm2 .. gemm3
  u16* dpre_bf = (u16*)p;    p += (size_t)4096 * 2048 * 2;   // gemm3 .. scan3
  u16* ybf = (u16*)p;        p += (size_t)4096 * 2048 * 2;   // scan3 .. gemm4
  float* sF = (float*)p;     p += (size_t)2 * NCH * 2048 * 16 * 4;  // scan1 .. carry, then outpre[0]
  float* aF = (float*)p;     p += (size_t)2 * NCH * 2048 * 16 * 4;  // scan1 .. carry, then outpre[1]
  float* carry = (float*)p;  p += (size_t)2 * NCH * 2048 * 16 * 4;  // carry .. scan3
  u16* Wx_bf = (u16*)p;      p += (size_t)2176 * 2048 * 2;
  u16* Wdt_bf = (u16*)p;     p += (size_t)2048 * 2048 * 2;
  u16* Wout_bf = (u16*)p;    p += (size_t)1024 * 2048 * 2;
  u16* x_bf = (u16*)p;       p += (size_t)4096 * 1024 * 2;   // cvt .. gemm1
  u16* Win_bf = (u16*)p;     p += (size_t)4096 * 1024 * 2;   // cvt .. gemm1
  float* outpre = sF;  // alias: sF/aF dead after carry; 2 split-K partials (2 x 16.8 MB)

  // 1) bf16 conversions (single fused launch)
  k_cvt_all<<<18688, 256, 0, stream>>>(x, x_bf, W_in, Win_bf, W_x, Wx_bf, W_dt, Wdt_bf,
                                       W_out, Wout_bf);

  // 2) xz = x @ W_in^T   (4096 x 4096, K=1024) -> bf16.  1024 blocks -> single-buffer.
  k_gemm_bt<true, false, false><<<dim3(32, 32), 256, 0, stream>>>(
      x_bf, 1024, Win_bf, 1024, nullptr, 0, 0, 0, xz_bf, 4096, 1024);
  // 3) depthwise conv + silu -> u (bf16)
  k_conv_silu<<<32768, 256, 0, stream>>>(xz_bf, conv_w, conv_b, u_bf);
  // 4) proj = u @ W_x^T  (4096 x 2176pad, K=2048): bf16 full (d_in) + fp32 cols 2048.. (B,C)
  k_gemm_bt<true, true, true><<<dim3(17, 32), 256, 0, stream>>>(
      u_bf, 2048, Wx_bf, 2048, projBC, 2048, 128, 0, projbf, 2176, 2048);
  // 5) dpre = d_in @ W_dt^T (4096 x 2048, K=2048) -> bf16
  k_gemm_bt<true, false, true><<<dim3(16, 32), 256, 0, stream>>>(
      projbf, 2176, Wdt_bf, 2048, nullptr, 0, 0, 0, dpre_bf, 2048, 2048);
  // 6) chunked selective scan (64 chunks x 32 steps), gate fused into pass 3
  k_scan1<<<dim3(8, NCH, 2), 256, 0, stream>>>(dpre_bf, b_dt, u_bf, projBC, A_log, sF, aF);
  k_scan_carry<<<256, 256, 0, stream>>>(sF, aF, carry);
  k_scan3<<<dim3(8, NCH, 2), 256, 0, stream>>>(dpre_bf, b_dt, u_bf, projBC, A_log, carry,
                                               Dv, xz_bf, ybf);
  // 7) outpre = ybf @ W_out^T (4096 x 1024, K=2048), split-K x2 -> 2 fp32 partials
  k_gemm_bt<false, true, true><<<dim3(8, 32, 2), 256, 0, stream>>>(
      ybf, 2048, Wout_bf, 2048, outpre, 0, 1024, (size_t)4096 * 1024, nullptr, 0, 1024);
  // 8) residual + layernorm (sums the 2 partials) -> d_out
  k_ln<<<4096, 256, 0, stream>>>(outpre, x, ln_g, ln_b, out);
}

// Round 4
// 453.298 us; speedup vs baseline: 2.8922x; 1.0660x over previous
//
#include <hip/hip_runtime.h>

typedef unsigned short u16;
typedef unsigned int u32;
typedef __bf16 bf16x8_t __attribute__((ext_vector_type(8)));
typedef float f32x4_t __attribute__((ext_vector_type(4)));

// ---- constants (problem shape) ----
// B=2, L=2048, D_MODEL=1024, D_INNER=2048, D_STATE=16, D_CONV=4
// ROWS = B*L = 4096; Wx padded 2080 -> 2176 rows
// scan: NC=64 chunks x CL=32 steps
// Algebraic restructure: dpre = u @ (W_dt @ Wx_din)^T  (weights-only GEMM precomputed),
// so the old 4096x2176 proj GEMM shrinks to the 32 B/C columns only.

#define NCH 64
#define CLEN 32

__device__ __forceinline__ u16 f2bf(float f) {
  u32 u = __float_as_uint(f);
  return (u16)((u + 0x7fffu + ((u >> 16) & 1u)) >> 16);  // RNE
}
__device__ __forceinline__ float bf2f(u16 h) { return __uint_as_float(((u32)h) << 16); }

__device__ __forceinline__ void async_ld16(const u16* g, u16* l) {
  __builtin_amdgcn_global_load_lds((const __attribute__((address_space(1))) void*)g,
                                   (__attribute__((address_space(3))) void*)l, 16, 0, 0);
}

// ---------------- fused converter: all 5 fp32->bf16 conversions ----------------
__global__ void k_cvt_all(const float* __restrict__ x, u16* __restrict__ x_bf,
                          const float* __restrict__ W_in, u16* __restrict__ Win_bf,
                          const float* __restrict__ W_x, u16* __restrict__ Wx_bf,
                          const float* __restrict__ W_dt, u16* __restrict__ Wdt_bf,
                          const float* __restrict__ W_out, u16* __restrict__ Wout_bf) {
  int g = blockIdx.x * 256 + threadIdx.x;
  const float* src;
  u16* dst;
  int rel;
  bool valid = true;
  if (g < 1048576) { src = x; dst = x_bf; rel = g; }
  else if (g < 2097152) { src = W_in; dst = Win_bf; rel = g - 1048576; }
  else if (g < 3211264) { src = W_x; dst = Wx_bf; rel = g - 2097152; valid = rel < 1064960; }
  else if (g < 4259840) { src = W_dt; dst = Wdt_bf; rel = g - 3211264; }
  else if (g < 4784128) { src = W_out; dst = Wout_bf; rel = g - 4259840; }
  else return;
  u32 lo = 0, hi = 0;
  if (valid) {
    float4 v = reinterpret_cast<const float4*>(src)[rel];
    lo = (u32)f2bf(v.x) | ((u32)f2bf(v.y) << 16);
    hi = (u32)f2bf(v.z) | ((u32)f2bf(v.w) << 16);
  }
  reinterpret_cast<uint2*>(dst)[rel] = make_uint2(lo, hi);
}

// ---------------- bf16 2048x2048 transpose (Wx_din -> WxT) ----------------
// out[j,k] = in[k,j]. 64x64 LDS tiles, 16B global accesses both sides.
__global__ void k_transpose(const u16* __restrict__ in, u16* __restrict__ out) {
  __shared__ u16 tile[64][72];  // +8 pad keeps 16B store alignment
  int bx = blockIdx.x;  // output-row (j) tile
  int by = blockIdx.y;  // output-col (k) tile
  int t = threadIdx.x;
#pragma unroll
  for (int i = 0; i < 2; ++i) {
    int idx = i * 256 + t;
    int r = idx >> 3;
    int c = (idx & 7) * 8;
    *reinterpret_cast<uint4*>(&tile[r][c]) =
        *reinterpret_cast<const uint4*>(in + (size_t)(by * 64 + r) * 2048 + bx * 64 + c);
  }
  __syncthreads();
#pragma unroll
  for (int i = 0; i < 2; ++i) {
    int idx = i * 256 + t;
    int r = idx >> 3;          // output row within tile (j)
    int c = (idx & 7) * 8;     // output col chunk (k)
    u16 tmp[8];
#pragma unroll
    for (int e = 0; e < 8; ++e) tmp[e] = tile[c + e][r];
    *reinterpret_cast<uint4*>(out + (size_t)(bx * 64 + r) * 2048 + by * 64 + c) =
        *reinterpret_cast<uint4*>(tmp);
  }
}

// ---------------- bf16 MFMA GEMM: C[M,N] = A[M,K] * B[N,K]^T ----------------
// m97 structure, single-buffer LDS (dbuf regressed: syncthreads drains the prefetch).
// Split-K via gridDim.z: z handles K cols from blockIdx.z*K; fp32 out offset z*fsplit.
template <bool WB, bool WF>
__global__ __launch_bounds__(256, 2) void k_gemm_bt(
    const u16* __restrict__ A, int lda, const u16* __restrict__ B, int ldb,
    float* __restrict__ Cf, int ldcf, size_t fsplit,
    u16* __restrict__ Cb, int ldc, int K) {
  __shared__ __align__(16) u16 sA[128 * 64];
  __shared__ __align__(16) u16 sB[128 * 64];
  const int tid = threadIdx.x;
  const int lane = tid & 63;
  const int wave = tid >> 6;
  const size_t tm = (size_t)blockIdx.y * 128;
  const size_t tn = (size_t)blockIdx.x * 128;
  const int kbase = blockIdx.z * K;
  const int wm = (wave & 1) * 64;
  const int wn = (wave >> 1) * 64;
  const int mrow = lane & 15;
  const int quad = lane >> 4;

  f32x4_t acc[4][4];
#pragma unroll
  for (int i = 0; i < 4; ++i)
#pragma unroll
    for (int j = 0; j < 4; ++j) {
      acc[i][j][0] = 0.f; acc[i][j][1] = 0.f; acc[i][j][2] = 0.f; acc[i][j][3] = 0.f;
    }

  for (int k0 = 0; k0 < K; k0 += 64) {
#pragma unroll
    for (int j = 0; j < 4; ++j) {
      int idx = j * 256 + tid;
      int row = idx >> 3;
      int col = (idx & 7) << 3;
      async_ld16(A + (tm + row) * (size_t)lda + (kbase + k0 + col), sA + (size_t)idx * 8);
      async_ld16(B + (tn + row) * (size_t)ldb + (kbase + k0 + col), sB + (size_t)idx * 8);
    }
    __syncthreads();
#pragma unroll
    for (int kk = 0; kk < 64; kk += 32) {
      bf16x8_t af[4], bfr[4];
#pragma unroll
      for (int i = 0; i < 4; ++i)
        af[i] = *reinterpret_cast<const bf16x8_t*>(sA + (wm + i * 16 + mrow) * 64 + kk + quad * 8);
#pragma unroll
      for (int i = 0; i < 4; ++i)
        bfr[i] = *reinterpret_cast<const bf16x8_t*>(sB + (wn + i * 16 + mrow) * 64 + kk + quad * 8);
#pragma unroll
      for (int i = 0; i < 4; ++i)
#pragma unroll
        for (int j = 0; j < 4; ++j)
          acc[i][j] = __builtin_amdgcn_mfma_f32_16x16x32_bf16(af[i], bfr[j], acc[i][j], 0, 0, 0);
    }
    __syncthreads();
  }

  // C/D layout: col = lane&15, row = quad*4 + reg  [measured m89/m91]
  if (WF) Cf += (size_t)blockIdx.z * fsplit;
#pragma unroll
  for (int i = 0; i < 4; ++i)
#pragma unroll
    for (int j = 0; j < 4; ++j) {
      size_t r0 = tm + wm + i * 16 + quad * 4;
      size_t c = tn + wn + j * 16 + mrow;
#pragma unroll
      for (int r = 0; r < 4; ++r) {
        float v = acc[i][j][r];
        if (WF) Cf[(r0 + r) * (size_t)ldcf + c] = v;
        if (WB) Cb[(r0 + r) * (size_t)ldc + c] = f2bf(v);
      }
    }
}

// ---------------- BC split-K reduce: projBC[r,c<32] = sum_z part[z][r,c] ----------------
__global__ void k_bc_reduce(const float* __restrict__ part, float* __restrict__ projBC) {
  int g = blockIdx.x * 256 + threadIdx.x;  // 4096 rows x 8 float4-chunks = 32768
  int r = g >> 3, c4 = (g & 7) * 4;
  size_t idx = (size_t)r * 128 + c4;
  float4 a = *reinterpret_cast<const float4*>(part + idx);
  float4 b = *reinterpret_cast<const float4*>(part + 524288 + idx);
  float4 c = *reinterpret_cast<const float4*>(part + 1048576 + idx);
  float4 d = *reinterpret_cast<const float4*>(part + 1572864 + idx);
  float4 o;
  o.x = a.x + b.x + c.x + d.x;
  o.y = a.y + b.y + c.y + d.y;
  o.z = a.z + b.z + c.z + d.z;
  o.w = a.w + b.w + c.w + d.w;
  *reinterpret_cast<float4*>(projBC + idx) = o;
}

// ---------------- depthwise causal conv(4) + silu, 8 channels/thread ----------------
// grid = B*L blocks, 256 threads (thread t -> channels 8t..8t+7); l is block-uniform.
__global__ void k_conv_silu(const u16* __restrict__ xz, const float* __restrict__ cw,
                            const float* __restrict__ cb, u16* __restrict__ u) {
  int bl = blockIdx.x;       // b*2048 + l
  int l = bl & 2047;
  int d0 = threadIdx.x * 8;
  float acc[8];
  float4 cb0 = *reinterpret_cast<const float4*>(cb + d0);
  float4 cb1 = *reinterpret_cast<const float4*>(cb + d0 + 4);
  acc[0] = cb0.x; acc[1] = cb0.y; acc[2] = cb0.z; acc[3] = cb0.w;
  acc[4] = cb1.x; acc[5] = cb1.y; acc[6] = cb1.z; acc[7] = cb1.w;
  float4 w[8];
#pragma unroll
  for (int i = 0; i < 8; ++i) w[i] = *reinterpret_cast<const float4*>(cw + (d0 + i) * 4);
#pragma unroll
  for (int k = 0; k < 4; ++k) {
    int lp = l + k - 3;
    if (lp >= 0) {
      bf16x8_t xv = *reinterpret_cast<const bf16x8_t*>(xz + ((size_t)(bl + k - 3) << 12) + d0);
#pragma unroll
      for (int i = 0; i < 8; ++i)
        acc[i] += (float)xv[i] * reinterpret_cast<const float*>(&w[i])[k];
    }
  }
  u16 tmp[8];
#pragma unroll
  for (int i = 0; i < 8; ++i) {
    float s = acc[i] / (1.f + __expf(-acc[i]));
    tmp[i] = f2bf(s);
  }
  *reinterpret_cast<uint4*>(u + ((size_t)bl << 11) + d0) = *reinterpret_cast<uint4*>(tmp);
}

// ---------------- chunked selective scan ----------------
__device__ __forceinline__ float softplus_fast(float x) {
  return __logf(1.f + __expf(x));
}

__global__ void k_scan1(const u16* __restrict__ dpre, const float* __restrict__ bdt,
                        const u16* __restrict__ u, const float* __restrict__ projBC,
                        const float* __restrict__ A_log, float* __restrict__ sF,
                        float* __restrict__ aF) {
  int d = blockIdx.x * 256 + threadIdx.x;
  int c = blockIdx.y, b = blockIdx.z;
  float A[16], s[16], ap[16];
#pragma unroll
  for (int q = 0; q < 4; ++q) {
    float4 al = reinterpret_cast<const float4*>(A_log + d * 16)[q];
    A[q * 4 + 0] = -__expf(al.x); A[q * 4 + 1] = -__expf(al.y);
    A[q * 4 + 2] = -__expf(al.z); A[q * 4 + 3] = -__expf(al.w);
  }
#pragma unroll
  for (int n = 0; n < 16; ++n) { s[n] = 0.f; ap[n] = 1.f; }
  float bd = bdt[d];
  int t0 = c * CLEN;
  for (int t = t0; t < t0 + CLEN; ++t) {
    size_t rb = (size_t)(b * 2048 + t);
    float delta = softplus_fast(bf2f(dpre[rb * 2048 + d]) + bd);
    float du = delta * bf2f(u[rb * 2048 + d]);
    const float4* Bp = reinterpret_cast<const float4*>(projBC + rb * 128);
    float4 B0 = Bp[0], B1 = Bp[1], B2 = Bp[2], B3 = Bp[3];
    float Bv[16] = {B0.x, B0.y, B0.z, B0.w, B1.x, B1.y, B1.z, B1.w,
                    B2.x, B2.y, B2.z, B2.w, B3.x, B3.y, B3.z, B3.w};
#pragma unroll
    for (int n = 0; n < 16; ++n) {
      float dA = __expf(delta * A[n]);
      s[n] = fmaf(s[n], dA, du * Bv[n]);
      ap[n] *= dA;
    }
  }
  size_t o = ((size_t)((b * NCH + c) * 2048 + d)) << 4;
#pragma unroll
  for (int q = 0; q < 4; ++q) {
    reinterpret_cast<float4*>(sF + o)[q] = make_float4(s[q * 4], s[q * 4 + 1], s[q * 4 + 2], s[q * 4 + 3]);
    reinterpret_cast<float4*>(aF + o)[q] = make_float4(ap[q * 4], ap[q * 4 + 1], ap[q * 4 + 2], ap[q * 4 + 3]);
  }
}

__global__ void k_scan_carry(const float* __restrict__ sF, const float* __restrict__ aF,
                             float* __restrict__ carry) {
  int g = blockIdx.x * 256 + threadIdx.x;  // 2 * 2048*16 = 65536
  int b = g >> 15;
  int dn = g & 32767;
  float S = 0.f;
#pragma unroll 4
  for (int c = 0; c < NCH; ++c) {
    size_t idx = ((size_t)(b * NCH + c) << 15) + dn;
    carry[idx] = S;
    S = S * aF[idx] + sF[idx];
  }
}

// scan3: recompute with carry-in, fuse  y = (scan + u*D) * silu(z)  -> bf16 (gemm4 input)
__global__ void k_scan3(const u16* __restrict__ dpre, const float* __restrict__ bdt,
                        const u16* __restrict__ u, const float* __restrict__ projBC,
                        const float* __restrict__ A_log, const float* __restrict__ carry,
                        const float* __restrict__ Dvec, const u16* __restrict__ xz,
                        u16* __restrict__ ybf) {
  int d = blockIdx.x * 256 + threadIdx.x;
  int c = blockIdx.y, b = blockIdx.z;
  float A[16], s[16];
#pragma unroll
  for (int q = 0; q < 4; ++q) {
    float4 al = reinterpret_cast<const float4*>(A_log + d * 16)[q];
    A[q * 4 + 0] = -__expf(al.x); A[q * 4 + 1] = -__expf(al.y);
    A[q * 4 + 2] = -__expf(al.z); A[q * 4 + 3] = -__expf(al.w);
  }
  size_t o = ((size_t)((b * NCH + c) * 2048 + d)) << 4;
#pragma unroll
  for (int q = 0; q < 4; ++q) {
    float4 cv = reinterpret_cast<const float4*>(carry + o)[q];
    s[q * 4] = cv.x; s[q * 4 + 1] = cv.y; s[q * 4 + 2] = cv.z; s[q * 4 + 3] = cv.w;
  }
  float bd = bdt[d];
  float Dd = Dvec[d];
  int t0 = c * CLEN;
  for (int t = t0; t < t0 + CLEN; ++t) {
    size_t rb = (size_t)(b * 2048 + t);
    float delta = softplus_fast(bf2f(dpre[rb * 2048 + d]) + bd);
    float uv = bf2f(u[rb * 2048 + d]);
    float du = delta * uv;
    const float4* Bp = reinterpret_cast<const float4*>(projBC + rb * 128);
    float4 B0 = Bp[0], B1 = Bp[1], B2 = Bp[2], B3 = Bp[3];
    float4 C0 = Bp[4], C1 = Bp[5], C2 = Bp[6], C3 = Bp[7];
    float Bv[16] = {B0.x, B0.y, B0.z, B0.w, B1.x, B1.y, B1.z, B1.w,
                    B2.x, B2.y, B2.z, B2.w, B3.x, B3.y, B3.z, B3.w};
    float Cv[16] = {C0.x, C0.y, C0.z, C0.w, C1.x, C1.y, C1.z, C1.w,
                    C2.x, C2.y, C2.z, C2.w, C3.x, C3.y, C3.z, C3.w};
    float yv = 0.f;
#pragma unroll
    for (int n = 0; n < 16; ++n) {
      float dA = __expf(delta * A[n]);
      s[n] = fmaf(s[n], dA, du * Bv[n]);
      yv = fmaf(s[n], Cv[n], yv);
    }
    yv += uv * Dd;
    float z = bf2f(xz[(rb << 12) + 2048 + d]);
    yv *= z / (1.f + __expf(-z));
    ybf[rb * 2048 + d] = f2bf(yv);
  }
}

// ---------------- residual + layernorm (sums 2 split-K partials) ----------------
__global__ void k_ln(const float* __restrict__ pre, const float* __restrict__ x,
                     const float* __restrict__ gam, const float* __restrict__ bet,
                     float* __restrict__ out) {
  int row = blockIdx.x, tid = threadIdx.x;
  size_t base = (size_t)row * 1024 + tid * 4;
  float4 v = *reinterpret_cast<const float4*>(pre + base);
  float4 p1 = *reinterpret_cast<const float4*>(pre + 4194304 + base);
  float4 r = *reinterpret_cast<const float4*>(x + base);
  v.x += p1.x + r.x; v.y += p1.y + r.y; v.z += p1.z + r.z; v.w += p1.w + r.w;
  float s = v.x + v.y + v.z + v.w;
  float s2 = v.x * v.x + v.y * v.y + v.z * v.z + v.w * v.w;
#pragma unroll
  for (int o = 32; o >= 1; o >>= 1) {
    s += __shfl_xor(s, o);
    s2 += __shfl_xor(s2, o);
  }
  __shared__ float red[8];
  int lane = tid & 63, wv = tid >> 6;
  if (lane == 0) { red[wv] = s; red[4 + wv] = s2; }
  __syncthreads();
  s = red[0] + red[1] + red[2] + red[3];
  s2 = red[4] + red[5] + red[6] + red[7];
  float mu = s * (1.f / 1024.f);
  float var = s2 * (1.f / 1024.f) - mu * mu;
  float rstd = rsqrtf(var + 1e-5f);
  float4 gg = *reinterpret_cast<const float4*>(gam + tid * 4);
  float4 bb = *reinterpret_cast<const float4*>(bet + tid * 4);
  float4 o;
  o.x = (v.x - mu) * rstd * gg.x + bb.x;
  o.y = (v.y - mu) * rstd * gg.y + bb.y;
  o.z = (v.z - mu) * rstd * gg.z + bb.z;
  o.w = (v.w - mu) * rstd * gg.w + bb.w;
  *reinterpret_cast<float4*>(out + base) = o;
}

extern "C" void kernel_launch(void* const* d_in, const int* in_sizes, int n_in,
                              void* d_out, int out_size, void* d_ws, size_t ws_size,
                              hipStream_t stream) {
  (void)in_sizes; (void)n_in; (void)out_size; (void)ws_size;
  const float* x = (const float*)d_in[0];
  const float* W_in = (const float*)d_in[1];
  const float* conv_w = (const float*)d_in[2];
  const float* conv_b = (const float*)d_in[3];
  const float* W_x = (const float*)d_in[4];
  const float* W_dt = (const float*)d_in[5];
  const float* b_dt = (const float*)d_in[6];
  const float* A_log = (const float*)d_in[7];
  const float* Dv = (const float*)d_in[8];
  const float* W_out = (const float*)d_in[9];
  const float* ln_g = (const float*)d_in[10];
  const float* ln_b = (const float*)d_in[11];
  float* out = (float*)d_out;

  // ---- workspace layout (~197 MB, lifetime-aliased) ----
  char* p = (char*)d_ws;
  u16* xz_bf = (u16*)p;      p += (size_t)4096 * 4096 * 2;   // gemm1 .. scan3 (z)
  u16* u_bf = (u16*)p;       p += (size_t)4096 * 2048 * 2;   // conv .. scan3
  float* projBC = (float*)p; p += (size_t)4096 * 128 * 4;    // bc_reduce .. scan3
  u16* dpre_bf = (u16*)p;    p += (size_t)4096 * 2048 * 2;   // dpre-gemm .. scan3
  u16* ybf = (u16*)p;        p += (size_t)4096 * 2048 * 2;   // scan3 .. gemm4
  float* sF = (float*)p;     p += (size_t)2 * NCH * 2048 * 16 * 4;  // scan1..carry; also BCpart, outpre
  float* aF = (float*)p;     p += (size_t)2 * NCH * 2048 * 16 * 4;  // scan1..carry; also outpre[1]
  float* carry = (float*)p;  p += (size_t)2 * NCH * 2048 * 16 * 4;  // carry .. scan3
  u16* Wx_bf = (u16*)p;      p += (size_t)2176 * 2048 * 2;
  u16* WxT_bf = (u16*)p;     p += (size_t)2048 * 2048 * 2;   // transpose .. weff
  u16* Weff_bf = (u16*)p;    p += (size_t)2048 * 2048 * 2;   // weff .. dpre-gemm
  u16* Wdt_bf = (u16*)p;     p += (size_t)2048 * 2048 * 2;
  u16* Wout_bf = (u16*)p;    p += (size_t)1024 * 2048 * 2;
  u16* x_bf = (u16*)p;       p += (size_t)4096 * 1024 * 2;   // cvt .. gemm1
  u16* Win_bf = (u16*)p;     p += (size_t)4096 * 1024 * 2;   // cvt .. gemm1
  float* BCpart = sF;            // alias: 4 partials x 4096x128 fp32 = 8.4 MB (pre-scan)
  float* outpre = sF;            // alias: 2 split-K partials (2 x 16.8 MB), post-carry

  // 1) bf16 conversions (single fused launch)
  k_cvt_all<<<18688, 256, 0, stream>>>(x, x_bf, W_in, Win_bf, W_x, Wx_bf, W_dt, Wdt_bf,
                                       W_out, Wout_bf);
  // 2) WxT = Wx_din^T (2048x2048 bf16)
  k_transpose<<<dim3(32, 32), 256, 0, stream>>>(Wx_bf, WxT_bf);
  // 3) W_eff = W_dt @ Wx_din  (2048x2048, K=2048) -> bf16   [weights-only]
  k_gemm_bt<true, false><<<dim3(16, 16), 256, 0, stream>>>(
      Wdt_bf, 2048, WxT_bf, 2048, nullptr, 0, 0, Weff_bf, 2048, 2048);
  // 4) xz = x @ W_in^T   (4096 x 4096, K=1024) -> bf16
  k_gemm_bt<true, false><<<dim3(32, 32), 256, 0, stream>>>(
      x_bf, 1024, Win_bf, 1024, nullptr, 0, 0, xz_bf, 4096, 1024);
  // 5) depthwise conv + silu -> u (bf16)
  k_conv_silu<<<4096, 256, 0, stream>>>(xz_bf, conv_w, conv_b, u_bf);
  // 6) BC = u @ Wx_BC^T (4096 x 128pad, K=2048), split-K x4 -> fp32 partials -> reduce
  k_gemm_bt<false, true><<<dim3(1, 32, 4), 256, 0, stream>>>(
      u_bf, 2048, Wx_bf + (size_t)2048 * 2048, 2048, BCpart, 128, (size_t)4096 * 128,
      nullptr, 0, 512);
  k_bc_reduce<<<128, 256, 0, stream>>>(BCpart, projBC);
  // 7) dpre = u @ W_eff^T (4096 x 2048, K=2048) -> bf16
  k_gemm_bt<true, false><<<dim3(16, 32), 256, 0, stream>>>(
      u_bf, 2048, Weff_bf, 2048, nullptr, 0, 0, dpre_bf, 2048, 2048);
  // 8) chunked selective scan (64 chunks x 32 steps), gate fused into pass 3
  k_scan1<<<dim3(8, NCH, 2), 256, 0, stream>>>(dpre_bf, b_dt, u_bf, projBC, A_log, sF, aF);
  k_scan_carry<<<256, 256, 0, stream>>>(sF, aF, carry);
  k_scan3<<<dim3(8, NCH, 2), 256, 0, stream>>>(dpre_bf, b_dt, u_bf, projBC, A_log, carry,
                                               Dv, xz_bf, ybf);
  // 9) outpre = ybf @ W_out^T (4096 x 1024, K=2048), split-K x2 -> 2 fp32 partials
  k_gemm_bt<false, true><<<dim3(8, 32, 2), 256, 0, stream>>>(
      ybf, 2048, Wout_bf, 2048, outpre, 1024, (size_t)4096 * 1024, nullptr, 0, 1024);
  // 10) residual + layernorm (sums the 2 partials) -> d_out
  k_ln<<<4096, 256, 0, stream>>>(outpre, x, ln_g, ln_b, out);
}

// Round 5
// 433.234 us; speedup vs baseline: 3.0261x; 1.0463x over previous
//
#include <hip/hip_runtime.h>

typedef unsigned short u16;
typedef unsigned int u32;
typedef __bf16 bf16x8_t __attribute__((ext_vector_type(8)));
typedef float f32x4_t __attribute__((ext_vector_type(4)));

// ---- constants (problem shape) ----
// B=2, L=2048, D_MODEL=1024, D_INNER=2048, D_STATE=16, D_CONV=4
// ROWS = B*L = 4096
// dpre = u @ (W_dt @ Wx_din)^T  (weights-only GEMM precomputed); BC columns fused
// into the dpre GEMM as cols 2048..2175 of Weff_ext (fp32 epilogue split).
// scan: NC=64 chunks x CL=32 steps

#define NCH 64
#define CLEN 32

__device__ __forceinline__ u16 f2bf(float f) {
  u32 u = __float_as_uint(f);
  return (u16)((u + 0x7fffu + ((u >> 16) & 1u)) >> 16);  // RNE
}
__device__ __forceinline__ float bf2f(u16 h) { return __uint_as_float(((u32)h) << 16); }

__device__ __forceinline__ void async_ld16(const u16* g, u16* l) {
  __builtin_amdgcn_global_load_lds((const __attribute__((address_space(1))) void*)g,
                                   (__attribute__((address_space(3))) void*)l, 16, 0, 0);
}

// ---------------- k_prep: all fp32->bf16 conversions + Wx_din transpose ----------------
// blocks [0,14592): float4-wise converts —
//   g <1048576: x -> x_bf | <2097152: W_in -> Win_bf | <3145728: W_dt -> Wdt_bf
//   <3670016: W_out -> Wout_bf | <3686400: W_x rows 2048..2079 (B,C) -> Weff_ext+2048*2048
//   <3735552: zero-fill Weff_ext rows 2080..2175
// blocks [14592,15616): 64x64-tile transpose of W_x din part (fp32 read, bf16 write) -> WxT
__global__ void k_prep(const float* __restrict__ x, u16* __restrict__ x_bf,
                       const float* __restrict__ W_in, u16* __restrict__ Win_bf,
                       const float* __restrict__ W_dt, u16* __restrict__ Wdt_bf,
                       const float* __restrict__ W_out, u16* __restrict__ Wout_bf,
                       const float* __restrict__ W_x, u16* __restrict__ WxT,
                       u16* __restrict__ Weff_ext) {
  __shared__ u16 tile[64][72];
  int blk = blockIdx.x;
  if (blk < 14592) {
    int g = blk * 256 + threadIdx.x;
    const float* src;
    u16* dst;
    int rel;
    bool rd = true;
    if (g < 1048576) { src = x; dst = x_bf; rel = g; }
    else if (g < 2097152) { src = W_in; dst = Win_bf; rel = g - 1048576; }
    else if (g < 3145728) { src = W_dt; dst = Wdt_bf; rel = g - 2097152; }
    else if (g < 3670016) { src = W_out; dst = Wout_bf; rel = g - 3145728; }
    else if (g < 3686400) { src = W_x + 4194304; dst = Weff_ext + (size_t)2048 * 2048; rel = g - 3670016; }
    else { dst = Weff_ext + (size_t)2080 * 2048; rel = g - 3686400; rd = false; src = x; }
    u32 lo = 0, hi = 0;
    if (rd) {
      float4 v = reinterpret_cast<const float4*>(src)[rel];
      lo = (u32)f2bf(v.x) | ((u32)f2bf(v.y) << 16);
      hi = (u32)f2bf(v.z) | ((u32)f2bf(v.w) << 16);
    }
    reinterpret_cast<uint2*>(dst)[rel] = make_uint2(lo, hi);
  } else {
    int bid = blk - 14592;
    int bx = bid & 31;   // output-row (j) tile
    int by = bid >> 5;   // output-col (k) tile
    int t = threadIdx.x;
#pragma unroll
    for (int i = 0; i < 4; ++i) {
      int idx = i * 256 + t;        // 0..1023 over 64x64 els in float4 chunks
      int r = idx >> 4;
      int c = (idx & 15) * 4;
      float4 v = *reinterpret_cast<const float4*>(W_x + (size_t)(by * 64 + r) * 2048 + bx * 64 + c);
      tile[r][c] = f2bf(v.x); tile[r][c + 1] = f2bf(v.y);
      tile[r][c + 2] = f2bf(v.z); tile[r][c + 3] = f2bf(v.w);
    }
    __syncthreads();
#pragma unroll
    for (int i = 0; i < 2; ++i) {
      int idx = i * 256 + t;
      int r = idx >> 3;
      int c = (idx & 7) * 8;
      u16 tmp[8];
#pragma unroll
      for (int e = 0; e < 8; ++e) tmp[e] = tile[c + e][r];
      *reinterpret_cast<uint4*>(WxT + (size_t)(bx * 64 + r) * 2048 + by * 64 + c) =
          *reinterpret_cast<uint4*>(tmp);
    }
  }
}

// ---------------- bf16 MFMA GEMM tile body: C[M,N] = A[M,K] * B[N,K]^T ----------------
// m97 structure, single-buffer LDS (explicit dbuf regressed: syncthreads drains prefetch).
// Epilogue split: cols < fcol0 -> bf16 Cb (ldc); cols >= fcol0 -> fp32 Cf at (c-fcol0, ldcf).
template <bool WB, bool WF>
__device__ __forceinline__ void gemm_tile(
    u16* sA, u16* sB, int bx, int by, int kbase,
    const u16* __restrict__ A, int lda, const u16* __restrict__ B, int ldb,
    float* __restrict__ Cf, int fcol0, int ldcf,
    u16* __restrict__ Cb, int ldc, int K) {
  const int tid = threadIdx.x;
  const int lane = tid & 63;
  const int wave = tid >> 6;
  const size_t tm = (size_t)by * 128;
  const size_t tn = (size_t)bx * 128;
  const int wm = (wave & 1) * 64;
  const int wn = (wave >> 1) * 64;
  const int mrow = lane & 15;
  const int quad = lane >> 4;

  f32x4_t acc[4][4];
#pragma unroll
  for (int i = 0; i < 4; ++i)
#pragma unroll
    for (int j = 0; j < 4; ++j) {
      acc[i][j][0] = 0.f; acc[i][j][1] = 0.f; acc[i][j][2] = 0.f; acc[i][j][3] = 0.f;
    }

  for (int k0 = 0; k0 < K; k0 += 64) {
#pragma unroll
    for (int j = 0; j < 4; ++j) {
      int idx = j * 256 + tid;
      int row = idx >> 3;
      int col = (idx & 7) << 3;
      async_ld16(A + (tm + row) * (size_t)lda + (kbase + k0 + col), sA + (size_t)idx * 8);
      async_ld16(B + (tn + row) * (size_t)ldb + (kbase + k0 + col), sB + (size_t)idx * 8);
    }
    __syncthreads();
#pragma unroll
    for (int kk = 0; kk < 64; kk += 32) {
      bf16x8_t af[4], bfr[4];
#pragma unroll
      for (int i = 0; i < 4; ++i)
        af[i] = *reinterpret_cast<const bf16x8_t*>(sA + (wm + i * 16 + mrow) * 64 + kk + quad * 8);
#pragma unroll
      for (int i = 0; i < 4; ++i)
        bfr[i] = *reinterpret_cast<const bf16x8_t*>(sB + (wn + i * 16 + mrow) * 64 + kk + quad * 8);
#pragma unroll
      for (int i = 0; i < 4; ++i)
#pragma unroll
        for (int j = 0; j < 4; ++j)
          acc[i][j] = __builtin_amdgcn_mfma_f32_16x16x32_bf16(af[i], bfr[j], acc[i][j], 0, 0, 0);
    }
    __syncthreads();
  }

  // C/D layout: col = lane&15, row = quad*4 + reg  [measured m89/m91]
#pragma unroll
  for (int i = 0; i < 4; ++i)
#pragma unroll
    for (int j = 0; j < 4; ++j) {
      size_t r0 = tm + wm + i * 16 + quad * 4;
      size_t c = tn + wn + j * 16 + mrow;
#pragma unroll
      for (int r = 0; r < 4; ++r) {
        float v = acc[i][j][r];
        if (WF && (int)c >= fcol0) Cf[(r0 + r) * (size_t)ldcf + (c - fcol0)] = v;
        if (WB && (int)c < fcol0) Cb[(r0 + r) * (size_t)ldc + c] = f2bf(v);
      }
    }
}

template <bool WB, bool WF>
__global__ __launch_bounds__(256, 2) void k_gemm(
    const u16* __restrict__ A, int lda, const u16* __restrict__ B, int ldb,
    float* __restrict__ Cf, int fcol0, int ldcf, size_t fsplit,
    u16* __restrict__ Cb, int ldc, int K) {
  __shared__ __align__(16) u16 sA[128 * 64];
  __shared__ __align__(16) u16 sB[128 * 64];
  gemm_tile<WB, WF>(sA, sB, blockIdx.x, blockIdx.y, blockIdx.z * K, A, lda, B, ldb,
                    Cf + (size_t)blockIdx.z * fsplit, fcol0, ldcf, Cb, ldc, K);
}

// gemm1 (xz = x@W_in^T, 1024 blocks) UNION weff (W_dt@Wx_din, 256 blocks) — independent.
__global__ __launch_bounds__(256, 2) void k_gemm_dual(
    const u16* __restrict__ A1, const u16* __restrict__ B1, u16* __restrict__ C1,
    const u16* __restrict__ A2, const u16* __restrict__ B2, u16* __restrict__ C2) {
  __shared__ __align__(16) u16 sA[128 * 64];
  __shared__ __align__(16) u16 sB[128 * 64];
  int b = blockIdx.x;
  if (b < 1024) {
    gemm_tile<true, false>(sA, sB, b & 31, b >> 5, 0, A1, 1024, B1, 1024,
                           nullptr, 1 << 30, 0, C1, 4096, 1024);
  } else {
    int b2 = b - 1024;
    gemm_tile<true, false>(sA, sB, b2 & 15, b2 >> 4, 0, A2, 2048, B2, 2048,
                           nullptr, 1 << 30, 0, C2, 2048, 2048);
  }
}

// ---------------- depthwise causal conv(4) + silu, 8 channels/thread ----------------
__global__ void k_conv_silu(const u16* __restrict__ xz, const float* __restrict__ cw,
                            const float* __restrict__ cb, u16* __restrict__ u) {
  int bl = blockIdx.x;       // b*2048 + l
  int l = bl & 2047;
  int d0 = threadIdx.x * 8;
  float acc[8];
  float4 cb0 = *reinterpret_cast<const float4*>(cb + d0);
  float4 cb1 = *reinterpret_cast<const float4*>(cb + d0 + 4);
  acc[0] = cb0.x; acc[1] = cb0.y; acc[2] = cb0.z; acc[3] = cb0.w;
  acc[4] = cb1.x; acc[5] = cb1.y; acc[6] = cb1.z; acc[7] = cb1.w;
  float4 w[8];
#pragma unroll
  for (int i = 0; i < 8; ++i) w[i] = *reinterpret_cast<const float4*>(cw + (d0 + i) * 4);
#pragma unroll
  for (int k = 0; k < 4; ++k) {
    int lp = l + k - 3;
    if (lp >= 0) {
      bf16x8_t xv = *reinterpret_cast<const bf16x8_t*>(xz + ((size_t)(bl + k - 3) << 12) + d0);
#pragma unroll
      for (int i = 0; i < 8; ++i)
        acc[i] += (float)xv[i] * reinterpret_cast<const float*>(&w[i])[k];
    }
  }
  u16 tmp[8];
#pragma unroll
  for (int i = 0; i < 8; ++i) {
    float s = acc[i] / (1.f + __expf(-acc[i]));
    tmp[i] = f2bf(s);
  }
  *reinterpret_cast<uint4*>(u + ((size_t)bl << 11) + d0) = *reinterpret_cast<uint4*>(tmp);
}

// ---------------- chunked selective scan ----------------
__device__ __forceinline__ float softplus_fast(float x) {
  return __logf(1.f + __expf(x));
}

__global__ void k_scan1(const u16* __restrict__ dpre, const float* __restrict__ bdt,
                        const u16* __restrict__ u, const float* __restrict__ projBC,
                        const float* __restrict__ A_log, float* __restrict__ sF,
                        float* __restrict__ aF) {
  int d = blockIdx.x * 256 + threadIdx.x;
  int c = blockIdx.y, b = blockIdx.z;
  float A[16], s[16], ap[16];
#pragma unroll
  for (int q = 0; q < 4; ++q) {
    float4 al = reinterpret_cast<const float4*>(A_log + d * 16)[q];
    A[q * 4 + 0] = -__expf(al.x); A[q * 4 + 1] = -__expf(al.y);
    A[q * 4 + 2] = -__expf(al.z); A[q * 4 + 3] = -__expf(al.w);
  }
#pragma unroll
  for (int n = 0; n < 16; ++n) { s[n] = 0.f; ap[n] = 1.f; }
  float bd = bdt[d];
  int t0 = c * CLEN;
  for (int t = t0; t < t0 + CLEN; ++t) {
    size_t rb = (size_t)(b * 2048 + t);
    float delta = softplus_fast(bf2f(dpre[rb * 2048 + d]) + bd);
    float du = delta * bf2f(u[rb * 2048 + d]);
    const float4* Bp = reinterpret_cast<const float4*>(projBC + rb * 128);
    float4 B0 = Bp[0], B1 = Bp[1], B2 = Bp[2], B3 = Bp[3];
    float Bv[16] = {B0.x, B0.y, B0.z, B0.w, B1.x, B1.y, B1.z, B1.w,
                    B2.x, B2.y, B2.z, B2.w, B3.x, B3.y, B3.z, B3.w};
#pragma unroll
    for (int n = 0; n < 16; ++n) {
      float dA = __expf(delta * A[n]);
      s[n] = fmaf(s[n], dA, du * Bv[n]);
      ap[n] *= dA;
    }
  }
  size_t o = ((size_t)((b * NCH + c) * 2048 + d)) << 4;
#pragma unroll
  for (int q = 0; q < 4; ++q) {
    reinterpret_cast<float4*>(sF + o)[q] = make_float4(s[q * 4], s[q * 4 + 1], s[q * 4 + 2], s[q * 4 + 3]);
    reinterpret_cast<float4*>(aF + o)[q] = make_float4(ap[q * 4], ap[q * 4 + 1], ap[q * 4 + 2], ap[q * 4 + 3]);
  }
}

__global__ void k_scan_carry(const float* __restrict__ sF, const float* __restrict__ aF,
                             float* __restrict__ carry) {
  int g = blockIdx.x * 256 + threadIdx.x;  // 2 * 2048*16 = 65536
  int b = g >> 15;
  int dn = g & 32767;
  float S = 0.f;
#pragma unroll 4
  for (int c = 0; c < NCH; ++c) {
    size_t idx = ((size_t)(b * NCH + c) << 15) + dn;
    carry[idx] = S;
    S = S * aF[idx] + sF[idx];
  }
}

// scan3: recompute with carry-in, fuse  y = (scan + u*D) * silu(z)  -> bf16 (gemm4 input)
__global__ void k_scan3(const u16* __restrict__ dpre, const float* __restrict__ bdt,
                        const u16* __restrict__ u, const float* __restrict__ projBC,
                        const float* __restrict__ A_log, const float* __restrict__ carry,
                        const float* __restrict__ Dvec, const u16* __restrict__ xz,
                        u16* __restrict__ ybf) {
  int d = blockIdx.x * 256 + threadIdx.x;
  int c = blockIdx.y, b = blockIdx.z;
  float A[16], s[16];
#pragma unroll
  for (int q = 0; q < 4; ++q) {
    float4 al = reinterpret_cast<const float4*>(A_log + d * 16)[q];
    A[q * 4 + 0] = -__expf(al.x); A[q * 4 + 1] = -__expf(al.y);
    A[q * 4 + 2] = -__expf(al.z); A[q * 4 + 3] = -__expf(al.w);
  }
  size_t o = ((size_t)((b * NCH + c) * 2048 + d)) << 4;
#pragma unroll
  for (int q = 0; q < 4; ++q) {
    float4 cv = reinterpret_cast<const float4*>(carry + o)[q];
    s[q * 4] = cv.x; s[q * 4 + 1] = cv.y; s[q * 4 + 2] = cv.z; s[q * 4 + 3] = cv.w;
  }
  float bd = bdt[d];
  float Dd = Dvec[d];
  int t0 = c * CLEN;
  for (int t = t0; t < t0 + CLEN; ++t) {
    size_t rb = (size_t)(b * 2048 + t);
    float delta = softplus_fast(bf2f(dpre[rb * 2048 + d]) + bd);
    float uv = bf2f(u[rb * 2048 + d]);
    float du = delta * uv;
    const float4* Bp = reinterpret_cast<const float4*>(projBC + rb * 128);
    float4 B0 = Bp[0], B1 = Bp[1], B2 = Bp[2], B3 = Bp[3];
    float4 C0 = Bp[4], C1 = Bp[5], C2 = Bp[6], C3 = Bp[7];
    float Bv[16] = {B0.x, B0.y, B0.z, B0.w, B1.x, B1.y, B1.z, B1.w,
                    B2.x, B2.y, B2.z, B2.w, B3.x, B3.y, B3.z, B3.w};
    float Cv[16] = {C0.x, C0.y, C0.z, C0.w, C1.x, C1.y, C1.z, C1.w,
                    C2.x, C2.y, C2.z, C2.w, C3.x, C3.y, C3.z, C3.w};
    float yv = 0.f;
#pragma unroll
    for (int n = 0; n < 16; ++n) {
      float dA = __expf(delta * A[n]);
      s[n] = fmaf(s[n], dA, du * Bv[n]);
      yv = fmaf(s[n], Cv[n], yv);
    }
    yv += uv * Dd;
    float z = bf2f(xz[(rb << 12) + 2048 + d]);
    yv *= z / (1.f + __expf(-z));
    ybf[rb * 2048 + d] = f2bf(yv);
  }
}

// ---------------- residual + layernorm (sums 2 split-K partials) ----------------
__global__ void k_ln(const float* __restrict__ pre, const float* __restrict__ x,
                     const float* __restrict__ gam, const float* __restrict__ bet,
                     float* __restrict__ out) {
  int row = blockIdx.x, tid = threadIdx.x;
  size_t base = (size_t)row * 1024 + tid * 4;
  float4 v = *reinterpret_cast<const float4*>(pre + base);
  float4 p1 = *reinterpret_cast<const float4*>(pre + 4194304 + base);
  float4 r = *reinterpret_cast<const float4*>(x + base);
  v.x += p1.x + r.x; v.y += p1.y + r.y; v.z += p1.z + r.z; v.w += p1.w + r.w;
  float s = v.x + v.y + v.z + v.w;
  float s2 = v.x * v.x + v.y * v.y + v.z * v.z + v.w * v.w;
#pragma unroll
  for (int o = 32; o >= 1; o >>= 1) {
    s += __shfl_xor(s, o);
    s2 += __shfl_xor(s2, o);
  }
  __shared__ float red[8];
  int lane = tid & 63, wv = tid >> 6;
  if (lane == 0) { red[wv] = s; red[4 + wv] = s2; }
  __syncthreads();
  s = red[0] + red[1] + red[2] + red[3];
  s2 = red[4] + red[5] + red[6] + red[7];
  float mu = s * (1.f / 1024.f);
  float var = s2 * (1.f / 1024.f) - mu * mu;
  float rstd = rsqrtf(var + 1e-5f);
  float4 gg = *reinterpret_cast<const float4*>(gam + tid * 4);
  float4 bb = *reinterpret_cast<const float4*>(bet + tid * 4);
  float4 o;
  o.x = (v.x - mu) * rstd * gg.x + bb.x;
  o.y = (v.y - mu) * rstd * gg.y + bb.y;
  o.z = (v.z - mu) * rstd * gg.z + bb.z;
  o.w = (v.w - mu) * rstd * gg.w + bb.w;
  *reinterpret_cast<float4*>(out + base) = o;
}

extern "C" void kernel_launch(void* const* d_in, const int* in_sizes, int n_in,
                              void* d_out, int out_size, void* d_ws, size_t ws_size,
                              hipStream_t stream) {
  (void)in_sizes; (void)n_in; (void)out_size; (void)ws_size;
  const float* x = (const float*)d_in[0];
  const float* W_in = (const float*)d_in[1];
  const float* conv_w = (const float*)d_in[2];
  const float* conv_b = (const float*)d_in[3];
  const float* W_x = (const float*)d_in[4];
  const float* W_dt = (const float*)d_in[5];
  const float* b_dt = (const float*)d_in[6];
  const float* A_log = (const float*)d_in[7];
  const float* Dv = (const float*)d_in[8];
  const float* W_out = (const float*)d_in[9];
  const float* ln_g = (const float*)d_in[10];
  const float* ln_b = (const float*)d_in[11];
  float* out = (float*)d_out;

  // ---- workspace layout (~184 MB, lifetime-aliased) ----
  char* p = (char*)d_ws;
  u16* xz_bf = (u16*)p;      p += (size_t)4096 * 4096 * 2;   // dual .. scan3 (z)
  u16* u_bf = (u16*)p;       p += (size_t)4096 * 2048 * 2;   // conv .. scan3
  float* projBC = (float*)p; p += (size_t)4096 * 128 * 4;    // gemm2 .. scan3
  u16* dpre_bf = (u16*)p;    p += (size_t)4096 * 2048 * 2;   // gemm2 .. scan3
  u16* ybf = (u16*)p;        p += (size_t)4096 * 2048 * 2;   // scan3 .. gemm4
  float* sF = (float*)p;     p += (size_t)2 * NCH * 2048 * 16 * 4;  // scan1..carry; then outpre[0]
  float* aF = (float*)p;     p += (size_t)2 * NCH * 2048 * 16 * 4;  // scan1..carry; then outpre[1]
  float* carry = (float*)p;  p += (size_t)2 * NCH * 2048 * 16 * 4;  // carry .. scan3
  u16* WxT_bf = (u16*)p;     p += (size_t)2048 * 2048 * 2;   // prep .. dual(weff)
  u16* Weff_ext = (u16*)p;   p += (size_t)2176 * 2048 * 2;   // prep(BC rows)+dual(weff) .. gemm2
  u16* Wdt_bf = (u16*)p;     p += (size_t)2048 * 2048 * 2;
  u16* Wout_bf = (u16*)p;    p += (size_t)1024 * 2048 * 2;
  u16* x_bf = (u16*)p;       p += (size_t)4096 * 1024 * 2;   // prep .. dual
  u16* Win_bf = (u16*)p;     p += (size_t)4096 * 1024 * 2;   // prep .. dual
  float* outpre = sF;  // alias: sF/aF dead after carry; 2 split-K partials (2 x 16.8 MB)

  // 1) conversions + Wx transpose + BC-row placement (single launch)
  k_prep<<<15616, 256, 0, stream>>>(x, x_bf, W_in, Win_bf, W_dt, Wdt_bf, W_out, Wout_bf,
                                    W_x, WxT_bf, Weff_ext);
  // 2) gemm1 (xz = x@W_in^T, 4096x4096 K=1024) UNION weff (W_dt@Wx_din -> Weff_ext rows 0..2047)
  k_gemm_dual<<<1280, 256, 0, stream>>>(x_bf, Win_bf, xz_bf, Wdt_bf, WxT_bf, Weff_ext);
  // 3) depthwise conv + silu -> u (bf16)
  k_conv_silu<<<4096, 256, 0, stream>>>(xz_bf, conv_w, conv_b, u_bf);
  // 4) combined: [dpre | BC] = u @ Weff_ext^T (4096 x 2176, K=2048)
  //    cols <2048 -> bf16 dpre; cols >=2048 -> fp32 projBC (128-wide)
  k_gemm<true, true><<<dim3(17, 32), 256, 0, stream>>>(
      u_bf, 2048, Weff_ext, 2048, projBC, 2048, 128, 0, dpre_bf, 2048, 2048);
  // 5) chunked selective scan (64 chunks x 32 steps), gate fused into pass 3
  k_scan1<<<dim3(8, NCH, 2), 256, 0, stream>>>(dpre_bf, b_dt, u_bf, projBC, A_log, sF, aF);
  k_scan_carry<<<256, 256, 0, stream>>>(sF, aF, carry);
  k_scan3<<<dim3(8, NCH, 2), 256, 0, stream>>>(dpre_bf, b_dt, u_bf, projBC, A_log, carry,
                                               Dv, xz_bf, ybf);
  // 6) outpre = ybf @ W_out^T (4096 x 1024, K=2048), split-K x2 -> 2 fp32 partials
  k_gemm<false, true><<<dim3(8, 32, 2), 256, 0, stream>>>(
      ybf, 2048, Wout_bf, 2048, outpre, 0, 1024, (size_t)4096 * 1024, nullptr, 0, 1024);
  // 7) residual + layernorm (sums the 2 partials) -> d_out
  k_ln<<<4096, 256, 0, stream>>>(outpre, x, ln_g, ln_b, out);
}